// Round 2
// baseline (986.463 us; speedup 1.0000x reference)
//
#include <hip/hip_runtime.h>
#include <hip/hip_bf16.h>
#include <math.h>

// EfficientMixedScoreMultiHeadAttentionLayer — round 2: dtype-adaptive (bf16/f32),
// fused-MLP f32 compute pipeline.
// B=8, R=C=200, E=256, H=16, D=16, MS_HID=32, SDIMS=2.
//   detect:  flags[0]=1 if float tensors are bf16 on device, else 0 (f32)
//            flags[1]=mask element byte size (1 = bool/u8, 4 = int32)
//   cvt:     up-convert all float inputs to f32 in ws
//   pack:    beta[j] = sum_h L1[j,2h+1]*alpha[h]; w1e[j][h] = L1[j,2h]
//   qkv:     q,v1 = x1@Wqv1.T (split); k,v2 = x2@Wkv2.T (split)   [b][row][256]
//   mixed:   dot_h = 0.25*q·k; hid_j = relu(w1e[j]·dot + beta_j*cost);
//            mixed[b,h,r,c] = hid·L2[h]   (stored bf16, + transposed copy)
//   combine: tanh*10, mask->-1e9, softmax, all-masked->0, @v, @Wout  (x2 dirs)

namespace {
constexpr int kB = 8, kR = 200, kC = 200, kE = 256, kH = 16;
constexpr int kHID = 512;
constexpr float kNEG = -1e9f;
constexpr float kNORM = 0.25f;   // 1/sqrt(16)
constexpr float kCLIP = 10.f;

__global__ void detect_kernel(const void* x1, const void* mask, int* flags) {
  if (threadIdx.x != 0) return;
  // Float dtype probe: interpret first 256 bf16 slots (512 B, in-bounds either
  // way). True-bf16 normals stay |v| < ~6; f32 bit-patterns read as bf16 give
  // huge/NaN values at even slots with overwhelming probability.
  const unsigned short* hb = (const unsigned short*)x1;
  float mx = 0.f;
  for (int i = 0; i < 256; ++i) {
    unsigned int u = ((unsigned int)hb[i]) << 16;
    float f = __uint_as_float(u);
    f = fabsf(f);
    if (!isfinite(f)) mx = 1e30f;
    else mx = fmaxf(mx, f);
  }
  flags[0] = (mx > 1000.f) ? 0 : 1;  // 1 => bf16 floats
  // Mask probe: int32 0/1 values have zero bytes at offsets i%4!=0.
  const unsigned char* mb = (const unsigned char*)mask;
  int nz = 0;
  for (int i = 0; i < 512; ++i)
    if ((i & 3) && mb[i]) nz++;
  flags[1] = nz ? 1 : 4;
}

__global__ __launch_bounds__(256) void cvt_kernel(const void* src, float* __restrict__ dst,
                                                  int n, const int* __restrict__ flags) {
  int i = blockIdx.x * blockDim.x + threadIdx.x;
  if (i >= n) return;
  if (flags[0]) {
    dst[i] = __bfloat162float(((const __hip_bfloat16*)src)[i]);
  } else {
    dst[i] = ((const float*)src)[i];
  }
}

__global__ __launch_bounds__(512) void pack_kernel(const float* __restrict__ L1,
                                                   const float* __restrict__ alpha,
                                                   float* __restrict__ w1e,
                                                   float* __restrict__ beta) {
  int j = threadIdx.x;  // 512 threads, one per hidden unit
  float bacc = 0.f;
#pragma unroll
  for (int h = 0; h < kH; ++h) {
    w1e[j * kH + h] = L1[j * 32 + 2 * h];
    bacc += L1[j * 32 + 2 * h + 1] * alpha[h];
  }
  beta[j] = bacc;
}

__global__ __launch_bounds__(256) void qkv_kernel(const float* __restrict__ x,
                                                  const float* __restrict__ W,
                                                  float* __restrict__ o0,
                                                  float* __restrict__ o1) {
  // grid (200, B); block 256. o0 = first 256 cols (q/k), o1 = last 256 (v).
  __shared__ float xl[kE];
  int row = blockIdx.x, b = blockIdx.y, tid = threadIdx.x;
  size_t base = ((size_t)b * kR + row) * kE;
  xl[tid] = x[base + tid];
  __syncthreads();
  const float4* x4 = reinterpret_cast<const float4*>(xl);
  const float4* W0 = reinterpret_cast<const float4*>(W + (size_t)tid * kE);
  const float4* W1 = reinterpret_cast<const float4*>(W + (size_t)(kE + tid) * kE);
  float a0 = 0.f, a1 = 0.f;
#pragma unroll 8
  for (int e = 0; e < kE / 4; ++e) {
    float4 xv = x4[e], w0 = W0[e], w1 = W1[e];
    a0 += xv.x * w0.x + xv.y * w0.y + xv.z * w0.z + xv.w * w0.w;
    a1 += xv.x * w1.x + xv.y * w1.y + xv.z * w1.z + xv.w * w1.w;
  }
  o0[base + tid] = a0;
  o1[base + tid] = a1;
}

__global__ __launch_bounds__(256) void mixed_kernel(
    const float* __restrict__ q, const float* __restrict__ k,
    const float* __restrict__ cost,
    const float* __restrict__ w1e, const float* __restrict__ beta,
    const float* __restrict__ L2,
    __hip_bfloat16* __restrict__ mixed, __hip_bfloat16* __restrict__ mixedT) {
  // grid (ceil(C/32)=7, ceil(R/16)=13, B); block 256 = 16r x 16c, 2 pairs/thread.
  int b = blockIdx.z;
  int r = blockIdx.y * 16 + (threadIdx.x >> 4);
  int cl = threadIdx.x & 15;
  int ca = blockIdx.x * 32 + cl, cb = ca + 16;
  bool vr = r < kR;
  bool va = vr && (ca < kC), vb = vr && (cb < kC);
  const float4* q4 = reinterpret_cast<const float4*>(q + ((size_t)b * kR + (vr ? r : 0)) * kE);
  const float4* k4a = reinterpret_cast<const float4*>(k + ((size_t)b * kC + (va ? ca : 0)) * kE);
  const float4* k4b = reinterpret_cast<const float4*>(k + ((size_t)b * kC + (vb ? cb : 0)) * kE);

  float dA[kH], dB[kH];
#pragma unroll
  for (int h = 0; h < kH; ++h) {
    float ta = 0.f, tb = 0.f;
#pragma unroll
    for (int i = 0; i < 4; ++i) {
      float4 qq = q4[h * 4 + i], ka = k4a[h * 4 + i], kb = k4b[h * 4 + i];
      ta += qq.x * ka.x + qq.y * ka.y + qq.z * ka.z + qq.w * ka.w;
      tb += qq.x * kb.x + qq.y * kb.y + qq.z * kb.z + qq.w * kb.w;
    }
    dA[h] = kNORM * ta;
    dB[h] = kNORM * tb;
  }
  float cA = va ? cost[((size_t)b * kR + r) * kC + ca] : 0.f;
  float cB = vb ? cost[((size_t)b * kR + r) * kC + cb] : 0.f;

  float mA[kH], mB[kH];
#pragma unroll
  for (int h = 0; h < kH; ++h) { mA[h] = 0.f; mB[h] = 0.f; }

  for (int j0 = 0; j0 < kHID; j0 += 4) {
    float ha[4], hb[4];
#pragma unroll
    for (int jj = 0; jj < 4; ++jj) {
      const float4* w1 = reinterpret_cast<const float4*>(w1e + (size_t)(j0 + jj) * kH);
      float bt = beta[j0 + jj];
      float ta = bt * cA, tb = bt * cB;
#pragma unroll
      for (int i = 0; i < 4; ++i) {
        float4 w = w1[i];
        ta += w.x * dA[4 * i] + w.y * dA[4 * i + 1] + w.z * dA[4 * i + 2] + w.w * dA[4 * i + 3];
        tb += w.x * dB[4 * i] + w.y * dB[4 * i + 1] + w.z * dB[4 * i + 2] + w.w * dB[4 * i + 3];
      }
      ha[jj] = fmaxf(ta, 0.f);
      hb[jj] = fmaxf(tb, 0.f);
    }
#pragma unroll
    for (int h = 0; h < kH; ++h) {
      float4 w2 = *reinterpret_cast<const float4*>(L2 + (size_t)h * kHID + j0);
      mA[h] += ha[0] * w2.x + ha[1] * w2.y + ha[2] * w2.z + ha[3] * w2.w;
      mB[h] += hb[0] * w2.x + hb[1] * w2.y + hb[2] * w2.z + hb[3] * w2.w;
    }
  }

#pragma unroll
  for (int h = 0; h < kH; ++h) {
    size_t bh = (size_t)b * kH + h;
    if (va) {
      mixed[(bh * kR + r) * kC + ca] = __float2bfloat16(mA[h]);
      mixedT[(bh * kC + ca) * kR + r] = __float2bfloat16(mA[h]);
    }
    if (vb) {
      mixed[(bh * kR + r) * kC + cb] = __float2bfloat16(mB[h]);
      mixedT[(bh * kC + cb) * kR + r] = __float2bfloat16(mB[h]);
    }
  }
}

__global__ __launch_bounds__(256) void combine_kernel(
    const __hip_bfloat16* __restrict__ logits,  // (B,H,200,200), softmax last dim
    const unsigned char* __restrict__ mask,     // (B,200,200), elt size flags[1]
    int sn, int sm,                              // mask elt idx = b*40000+n*sn+m*sm
    const float* __restrict__ v,                 // (B,200,256)
    const float* __restrict__ Wout,              // (256,256)
    void* __restrict__ out, int outOff,          // out elt idx offset
    const int* __restrict__ flags) {
  __shared__ float wsm[kH][kC];
  __shared__ float pre[kE];
  int n = blockIdx.x, b = blockIdx.y, tid = threadIdx.x;
  int g = tid >> 4, l = tid & 15;  // head g, lane-in-group l
  int isbf = flags[0];
  int ms = flags[1];

  const __hip_bfloat16* lg = logits + (((size_t)b * kH + g) * 200 + n) * 200;
  const unsigned char* mk = mask + ((size_t)b * 40000 + (size_t)n * sn) * ms;

  float mx = kNEG;
  for (int m = l; m < 200; m += 16) {
    bool masked = mk[(size_t)m * sm * ms] != 0;
    float x = masked ? kNEG : tanhf(__bfloat162float(lg[m])) * kCLIP;
    wsm[g][m] = x;
    mx = fmaxf(mx, x);
  }
#pragma unroll
  for (int o = 8; o >= 1; o >>= 1) mx = fmaxf(mx, __shfl_xor(mx, o, 16));
  float se = 0.f;
  for (int m = l; m < 200; m += 16) {
    float e = expf(wsm[g][m] - mx);
    wsm[g][m] = e;
    se += e;
  }
#pragma unroll
  for (int o = 8; o >= 1; o >>= 1) se += __shfl_xor(se, o, 16);
  float inv = (mx <= -1e8f) ? 0.f : 1.f / se;  // all-masked row -> zero weights
  for (int m = l; m < 200; m += 16) wsm[g][m] *= inv;
  __syncthreads();

  // pre[f] = sum_m w[h][m] * v[b][m][f], f = tid (h = tid>>4)
  float acc = 0.f;
  const float* vp = v + (size_t)b * 200 * kE + tid;
#pragma unroll 4
  for (int m = 0; m < 200; ++m) acc += wsm[g][m] * vp[(size_t)m * kE];
  pre[tid] = acc;
  __syncthreads();

  const float4* p4 = reinterpret_cast<const float4*>(pre);
  const float4* w4 = reinterpret_cast<const float4*>(Wout + (size_t)tid * kE);
  float oacc = 0.f;
#pragma unroll 8
  for (int i = 0; i < kE / 4; ++i) {
    float4 a = p4[i], w = w4[i];
    oacc += a.x * w.x + a.y * w.y + a.z * w.z + a.w * w.w;
  }
  size_t oidx = (size_t)outOff + ((size_t)b * 200 + n) * kE + tid;
  if (isbf) ((__hip_bfloat16*)out)[oidx] = __float2bfloat16(oacc);
  else ((float*)out)[oidx] = oacc;
}

}  // namespace

extern "C" void kernel_launch(void* const* d_in, const int* in_sizes, int n_in,
                              void* d_out, int out_size, void* d_ws, size_t ws_size,
                              hipStream_t stream) {
  const unsigned char* mask = (const unsigned char*)d_in[2];

  // ws layout (f32 elements unless noted)
  float* ws = (float*)d_ws;
  float* x1c = ws;                    // 409600
  float* x2c = x1c + 409600;          // 409600
  float* costc = x2c + 409600;        // 320000
  float* Wqv1c = costc + 320000;      // 131072
  float* Wkv2c = Wqv1c + 131072;      // 131072
  float* L1c = Wkv2c + 131072;        // 16384
  float* L2c = L1c + 16384;           // 8192
  float* alphac = L2c + 8192;         // 16
  float* o1wc = alphac + 16;          // 65536
  float* o2wc = o1wc + 65536;         // 65536  -> end 1,557,008
  float* q = o2wc + 65536;            // 409600
  float* v1 = q + 409600;
  float* k = v1 + 409600;
  float* v2 = k + 409600;             // -> end 3,195,408
  float* w1e = v2 + 409600;           // 8192
  float* beta = w1e + 8192;           // 512
  int* flags = (int*)(beta + 512);    // 16 ints
  __hip_bfloat16* mixed = (__hip_bfloat16*)(flags + 16);   // 5,120,000 bf16
  __hip_bfloat16* mixedT = mixed + 5120000;                // 5,120,000 bf16
  size_t need = (size_t)(3204128) * 4 + (size_t)5120000 * 2 * 2;  // 33,296,512 B
  if (ws_size < need) return;  // output stays zero -> loud failure

  detect_kernel<<<dim3(1), 64, 0, stream>>>(d_in[0], d_in[2], flags);

  auto cvt = [&](const void* s, float* d, int n) {
    cvt_kernel<<<dim3((n + 255) / 256), 256, 0, stream>>>(s, d, n, flags);
  };
  cvt(d_in[0], x1c, 409600);
  cvt(d_in[1], x2c, 409600);
  cvt(d_in[3], costc, 320000);
  cvt(d_in[4], Wqv1c, 131072);
  cvt(d_in[5], Wkv2c, 131072);
  cvt(d_in[6], L1c, 16384);
  cvt(d_in[7], L2c, 8192);
  cvt(d_in[8], alphac, 16);
  cvt(d_in[9], o1wc, 65536);
  cvt(d_in[10], o2wc, 65536);

  pack_kernel<<<dim3(1), 512, 0, stream>>>(L1c, alphac, w1e, beta);
  qkv_kernel<<<dim3(200, kB), 256, 0, stream>>>(x1c, Wqv1c, q, v1);
  qkv_kernel<<<dim3(200, kB), 256, 0, stream>>>(x2c, Wkv2c, k, v2);
  mixed_kernel<<<dim3(7, 13, kB), 256, 0, stream>>>(q, k, costc, w1e, beta, L2c,
                                                    mixed, mixedT);
  combine_kernel<<<dim3(200, kB), 256, 0, stream>>>(mixed, mask, 200, 1, v2, o1wc,
                                                    d_out, 0, flags);
  combine_kernel<<<dim3(200, kB), 256, 0, stream>>>(mixedT, mask, 1, 200, v1, o2wc,
                                                    d_out, 409600, flags);
}

// Round 5
// 530.877 us; speedup vs baseline: 1.8582x; 1.8582x over previous
//
#include <hip/hip_runtime.h>
#include <hip/hip_bf16.h>
#include <math.h>

// EfficientMixedScoreMultiHeadAttentionLayer — round 5: MFMA mixed stage in FP16
// (4x the mantissa of bf16; same MFMA rate; structure identical to round 4,
// whose output was correct to precision level).
// B=8, R=C=200, E=256, H=16, D=16, MS_HID=32, SDIMS=2.
//
// mixed stage as 3 chained MFMAs per 16x16 pair tile (1 wave/block):
//   QK:    dot_h[16r x 16c] = (0.25*q_h) . k_h    (K=16 padded to 32)
//   GEMM1: hid^T[16u x 16p] = W~ x scores^T       (K=32: feats = 16 dots, cost, 0s)
//   GEMM2: mixed^T[16h x 16p] += L2 x hid^T       (K=512 = 16 steps)
// Hidden dim is PERMUTED in packed weights so GEMM1's C fragment
// (col=lane&15=pair, row=4g+t) is directly GEMM2's B fragment (k=8g+j,
// col=pair) after relu+f16 cast: unit u = k2*32 + 8*(rho>>2) + 4*m + (rho&3)
// lives at GEMM1 tile tau=2*k2+m, row rho. L2 side is identity.

namespace {
constexpr int kB = 8, kR = 200, kC = 200, kE = 256, kH = 16;
constexpr float kNEG = -1e9f;
constexpr float kCLIP = 10.f;

typedef _Float16 f16x8 __attribute__((ext_vector_type(8)));
typedef _Float16 f16x4 __attribute__((ext_vector_type(4)));
typedef float f32x4 __attribute__((ext_vector_type(4)));
typedef unsigned int u32;

// ---- ws layout (f32 element offsets; cvt_all relies on 0..9 being contiguous)
constexpr int X1C = 0;
constexpr int X2C = 409600;
constexpr int COSTC = 819200;
constexpr int WQV1C = 1139200;
constexpr int WKV2C = 1270272;
constexpr int L1C = 1401344;
constexpr int L2C = 1417728;
constexpr int ALPHAC = 1425920;
constexpr int O1WC = 1425936;
constexpr int O2WC = 1491472;
constexpr int CVT_TOTAL = 1557008;
constexpr int V1 = 1557008;
constexpr int V2 = 1966608;
constexpr int BETA = 2376208;
constexpr int FLAGS = 2376720;        // 16 ints
constexpr int F32_END = 2376736;
// f16 element offsets from h base
constexpr int QH = 0;
constexpr int KH = 409600;
constexpr int W1PACK = 819200;        // 32 tiles x 64 lanes x 8
constexpr int L2PACK = 835584;        // 16 steps x 64 lanes x 8
constexpr int MIXED = 843776;         // 5,120,000
constexpr int MIXEDT = 5963776;       // 5,120,000
constexpr size_t F16_END = 11083776;
constexpr size_t WS_NEED = (size_t)F32_END * 4 + F16_END * 2;  // 31,674,496 B

__device__ inline _Float16 f2h(float v) { return (_Float16)v; }
__device__ inline u32 pack2(float lo, float hi) {
  return (u32)__builtin_bit_cast(unsigned short, (_Float16)lo) |
         ((u32)__builtin_bit_cast(unsigned short, (_Float16)hi) << 16);
}

__global__ void detect_kernel(const unsigned short* x1h, const unsigned char* mb,
                              int* flags) {
  int l = threadIdx.x;  // 64
  int bad = 0;
  for (int i = l; i < 256; i += 64) {
    float f = __uint_as_float(((u32)x1h[i]) << 16);
    if (!(fabsf(f) <= 1000.f)) bad = 1;  // catches NaN/inf too
  }
  unsigned long long vb = __ballot(bad);
  int nz = 0;
  for (int i = l; i < 512; i += 64)
    if ((i & 3) && mb[i]) nz = 1;
  unsigned long long vn = __ballot(nz);
  if (l == 0) {
    flags[0] = vb ? 0 : 1;  // 1 => float tensors are bf16
    flags[1] = vn ? 1 : 4;  // mask element byte size
  }
}

__global__ __launch_bounds__(256) void cvt_all_kernel(
    const void* s0, const void* s1, const void* s2, const void* s3,
    const void* s4, const void* s5, const void* s6, const void* s7,
    const void* s8, const void* s9, float* __restrict__ ws,
    const int* __restrict__ flags) {
  int i = blockIdx.x * 256 + threadIdx.x;
  if (i >= CVT_TOTAL) return;
  const void* src;
  int off;
  if (i < COSTC) {
    if (i < X2C) { src = s0; off = i; }
    else { src = s1; off = i - X2C; }
  } else if (i < WKV2C) {
    if (i < WQV1C) { src = s2; off = i - COSTC; }
    else { src = s3; off = i - WQV1C; }
  } else if (i < L2C) {
    if (i < L1C) { src = s4; off = i - WKV2C; }
    else { src = s5; off = i - L1C; }
  } else if (i < O1WC) {
    if (i < ALPHAC) { src = s6; off = i - L2C; }
    else { src = s7; off = i - ALPHAC; }
  } else {
    if (i < O2WC) { src = s8; off = i - O1WC; }
    else { src = s9; off = i - O2WC; }
  }
  float v = flags[0] ? __bfloat162float(((const __hip_bfloat16*)src)[off])
                     : ((const float*)src)[off];
  ws[i] = v;
}

__global__ __launch_bounds__(512) void pack_beta_kernel(const float* __restrict__ L1,
                                                        const float* __restrict__ alpha,
                                                        float* __restrict__ beta) {
  int j = threadIdx.x;  // 512
  float acc = 0.f;
#pragma unroll
  for (int h = 0; h < kH; ++h) acc += L1[j * 32 + 2 * h + 1] * alpha[h];
  beta[j] = acc;
}

__global__ __launch_bounds__(256) void pack_w1_kernel(const float* __restrict__ L1,
                                                      const float* __restrict__ beta,
                                                      _Float16* __restrict__ w1pack) {
  int idx = blockIdx.x * 256 + threadIdx.x;  // 2048 = 32 tiles x 64 lanes
  if (idx >= 2048) return;
  int tau = idx >> 6, l = idx & 63;
  int rho = l & 15, gg = l >> 4;
  int k2 = tau >> 1, m = tau & 1;
  int u = k2 * 32 + 8 * (rho >> 2) + 4 * m + (rho & 3);
#pragma unroll
  for (int j = 0; j < 8; ++j) {
    int feat = 8 * gg + j;
    float v = (feat < 16) ? L1[u * 32 + 2 * feat] : (feat == 16 ? beta[u] : 0.f);
    w1pack[idx * 8 + j] = f2h(v);
  }
}

__global__ __launch_bounds__(256) void pack_l2_kernel(const float* __restrict__ L2,
                                                      _Float16* __restrict__ l2pack) {
  int idx = blockIdx.x * 256 + threadIdx.x;  // 1024 = 16 steps x 64 lanes
  if (idx >= 1024) return;
  int k2 = idx >> 6, l = idx & 63;
  int head = l & 15, gg = l >> 4;
#pragma unroll
  for (int j = 0; j < 8; ++j)
    l2pack[idx * 8 + j] = f2h(L2[head * 512 + k2 * 32 + 8 * gg + j]);
}

__global__ __launch_bounds__(256) void qkv_kernel(const float* __restrict__ x,
                                                  const float* __restrict__ W,
                                                  _Float16* __restrict__ oh,  // [b][h][row][d] f16
                                                  float* __restrict__ ov,     // [b][row][256] f32
                                                  float scale) {
  __shared__ float xl[kE];
  int row = blockIdx.x, b = blockIdx.y, tid = threadIdx.x;
  size_t base = ((size_t)b * kR + row) * kE;
  xl[tid] = x[base + tid];
  __syncthreads();
  const float4* x4 = reinterpret_cast<const float4*>(xl);
  const float4* W0 = reinterpret_cast<const float4*>(W + (size_t)tid * kE);
  const float4* W1 = reinterpret_cast<const float4*>(W + (size_t)(kE + tid) * kE);
  float a0 = 0.f, a1 = 0.f;
#pragma unroll 8
  for (int e = 0; e < kE / 4; ++e) {
    float4 xv = x4[e], w0 = W0[e], w1 = W1[e];
    a0 += xv.x * w0.x + xv.y * w0.y + xv.z * w0.z + xv.w * w0.w;
    a1 += xv.x * w1.x + xv.y * w1.y + xv.z * w1.z + xv.w * w1.w;
  }
  // q/k channel tid = h*16+d -> [b][h][row][d]
  oh[((b * 16 + (tid >> 4)) * 200 + row) * 16 + (tid & 15)] = f2h(scale * a0);
  ov[base + tid] = a1;
}

// ---- the MFMA mixed kernel: 1 wave/block, 16r x 16c tile --------------------
__global__ __launch_bounds__(64) void mixed_mfma_kernel(
    const _Float16* __restrict__ qh, const _Float16* __restrict__ kh,
    const float* __restrict__ costc,
    const _Float16* __restrict__ w1pack, const _Float16* __restrict__ l2pack,
    _Float16* __restrict__ mixed, _Float16* __restrict__ mixedT) {
  __shared__ _Float16 scores[4096];           // [r16][p16][f16], XOR-swizzled
  __shared__ _Float16 mixtile[16 * 16 * 20];  // [h][c][r pad 20]

  const int l = threadIdx.x;
  const int p = l & 15;   // pair / col
  const int g = l >> 4;   // lane group
  const int b = blockIdx.z;
  const int r0 = blockIdx.y * 16, c0 = blockIdx.x * 16;
  const f32x4 fzero = {0.f, 0.f, 0.f, 0.f};
  const f16x8 hzero = {0, 0, 0, 0, 0, 0, 0, 0};

  // preload packed weight fragments (192 VGPRs; fits without spills at
  // launch_bounds(64) -> up to 512-reg budget)
  f16x8 w1f[32], l2f[16];
  {
    const f16x8* wp = reinterpret_cast<const f16x8*>(w1pack) + l;
#pragma unroll
    for (int t = 0; t < 32; ++t) w1f[t] = wp[t * 64];
    const f16x8* lp = reinterpret_cast<const f16x8*>(l2pack) + l;
#pragma unroll
    for (int t = 0; t < 16; ++t) l2f[t] = lp[t * 64];
  }

  // ---- QK phase: dot_h for the whole 16x16 tile, staged to scores LDS
  int qrow = r0 + p; if (qrow > 199) qrow = 199;
  int krow = c0 + p; if (krow > 199) krow = 199;
  for (int hc = 0; hc < 4; ++hc) {
    f32x4 acc[4];
#pragma unroll
    for (int i = 0; i < 4; ++i) {
      int h = hc * 4 + i;
      f16x8 qf = hzero, kf = hzero;
      if (g < 2) {
        qf = *reinterpret_cast<const f16x8*>(qh + ((b * 16 + h) * 200 + qrow) * 16 + 8 * g);
        kf = *reinterpret_cast<const f16x8*>(kh + ((b * 16 + h) * 200 + krow) * 16 + 8 * g);
      }
      acc[i] = __builtin_amdgcn_mfma_f32_16x16x32_f16(qf, kf, fzero, 0, 0, 0);
    }
    // write 4 heads (2 packed pairs); cell (rho=4g+t, p, f=h), swz on byte addr
#pragma unroll
    for (int pr = 0; pr < 2; ++pr) {
      int h = hc * 4 + pr * 2;
#pragma unroll
      for (int t = 0; t < 4; ++t) {
        u32 pk = pack2(acc[pr * 2][t], acc[pr * 2 + 1][t]);
        u32 a = (u32)((4 * g + t) * 512 + p * 32 + h * 2) ^ (((p >> 2) & 3) << 4);
        *reinterpret_cast<u32*>(reinterpret_cast<char*>(scores) + a) = pk;
      }
    }
  }
  __syncthreads();

  // ---- main loop: per r-subtile, GEMM1 (x2) -> relu/pack -> GEMM2
  for (int r = 0; r < 16; ++r) {
    u32 a = (u32)(r * 512 + p * 32 + (g & 1) * 16) ^ (((p >> 2) & 3) << 4);
    f16x8 sfrag = *reinterpret_cast<const f16x8*>(reinterpret_cast<char*>(scores) + a);
    int rr = r0 + r; if (rr > 199) rr = 199;
    int cc = c0 + p; if (cc > 199) cc = 199;
    float cv = costc[(b * 200 + rr) * 200 + cc];
    f16x8 bfrag;
    if (g < 2) bfrag = sfrag;
    else if (g == 2) { bfrag = hzero; bfrag[0] = f2h(cv); }  // k-slot 16 = cost
    else bfrag = hzero;

    f32x4 macc = fzero;
#pragma unroll
    for (int k2 = 0; k2 < 16; ++k2) {
      f32x4 h0 = __builtin_amdgcn_mfma_f32_16x16x32_f16(w1f[2 * k2], bfrag, fzero, 0, 0, 0);
      f32x4 h1 = __builtin_amdgcn_mfma_f32_16x16x32_f16(w1f[2 * k2 + 1], bfrag, fzero, 0, 0, 0);
      f16x8 pf;
      pf[0] = f2h(fmaxf(h0[0], 0.f));
      pf[1] = f2h(fmaxf(h0[1], 0.f));
      pf[2] = f2h(fmaxf(h0[2], 0.f));
      pf[3] = f2h(fmaxf(h0[3], 0.f));
      pf[4] = f2h(fmaxf(h1[0], 0.f));
      pf[5] = f2h(fmaxf(h1[1], 0.f));
      pf[6] = f2h(fmaxf(h1[2], 0.f));
      pf[7] = f2h(fmaxf(h1[3], 0.f));
      macc = __builtin_amdgcn_mfma_f32_16x16x32_f16(l2f[k2], pf, macc, 0, 0, 0);
    }
    // macc: lane -> mixed^T[head=4g+t][pair=p] for this r
    bool vr = (r0 + r) < 200, vc = (c0 + p) < 200;
#pragma unroll
    for (int t = 0; t < 4; ++t) {
      int h = 4 * g + t;
      _Float16 mb = f2h(macc[t]);
      if (vr && vc)
        mixed[((size_t)(b * 16 + h) * 200 + (r0 + r)) * 200 + (c0 + p)] = mb;
      mixtile[(h * 16 + p) * 20 + r] = mb;
    }
  }
  __syncthreads();

  // ---- coalesced mixedT stores: [bh][c][r], 16 r's per (h,c)
#pragma unroll
  for (int i = 0; i < 4; ++i) {
    int idx = i * 64 + l, h = idx >> 4, c = idx & 15;
    if ((c0 + c) < 200) {
      const _Float16* src = &mixtile[(h * 16 + c) * 20];
      f16x4 a0 = *reinterpret_cast<const f16x4*>(src);
      f16x4 a1 = *reinterpret_cast<const f16x4*>(src + 4);
      f16x4 a2 = *reinterpret_cast<const f16x4*>(src + 8);
      f16x4 a3 = *reinterpret_cast<const f16x4*>(src + 12);
      _Float16* dst = mixedT + ((size_t)(b * 16 + h) * 200 + (c0 + c)) * 200 + r0;
      *reinterpret_cast<f16x4*>(dst) = a0;
      *(reinterpret_cast<f16x4*>(dst) + 1) = a1;
      if (r0 + 15 < 200) {
        *(reinterpret_cast<f16x4*>(dst) + 2) = a2;
        *(reinterpret_cast<f16x4*>(dst) + 3) = a3;
      }
    }
  }
}

__global__ __launch_bounds__(256) void combine_kernel(
    const _Float16* __restrict__ logits,     // (B,H,200,200), softmax last dim
    const unsigned char* __restrict__ mask,  // (B,200,200), elt size flags[1]
    int sn, int sm,                          // mask elt idx = b*40000+n*sn+m*sm
    const float* __restrict__ v,             // (B,200,256)
    const float* __restrict__ Wout,          // (256,256)
    void* __restrict__ out, int outOff, const int* __restrict__ flags) {
  __shared__ float wsm[kH][kC];
  __shared__ float pre[kE];
  int n = blockIdx.x, b = blockIdx.y, tid = threadIdx.x;
  int gg = tid >> 4, ll = tid & 15;
  int isbf = flags[0];
  int ms = flags[1];

  const _Float16* lg = logits + (((size_t)b * kH + gg) * 200 + n) * 200;
  const unsigned char* mk = mask + ((size_t)b * 40000 + (size_t)n * sn) * ms;

  float mx = kNEG;
  for (int m = ll; m < 200; m += 16) {
    bool masked = mk[(size_t)m * sm * ms] != 0;
    float x = masked ? kNEG : tanhf((float)lg[m]) * kCLIP;
    wsm[gg][m] = x;
    mx = fmaxf(mx, x);
  }
#pragma unroll
  for (int o = 8; o >= 1; o >>= 1) mx = fmaxf(mx, __shfl_xor(mx, o, 16));
  float se = 0.f;
  for (int m = ll; m < 200; m += 16) {
    float e = expf(wsm[gg][m] - mx);
    wsm[gg][m] = e;
    se += e;
  }
#pragma unroll
  for (int o = 8; o >= 1; o >>= 1) se += __shfl_xor(se, o, 16);
  float inv = (mx <= -1e8f) ? 0.f : 1.f / se;
  for (int m = ll; m < 200; m += 16) wsm[gg][m] *= inv;
  __syncthreads();

  float acc = 0.f;
  const float* vp = v + (size_t)b * 200 * kE + tid;
#pragma unroll 4
  for (int m = 0; m < 200; ++m) acc += wsm[gg][m] * vp[(size_t)m * kE];
  pre[tid] = acc;
  __syncthreads();

  const float4* p4 = reinterpret_cast<const float4*>(pre);
  const float4* w4 = reinterpret_cast<const float4*>(Wout + (size_t)tid * kE);
  float oacc = 0.f;
#pragma unroll 8
  for (int i = 0; i < kE / 4; ++i) {
    float4 a = p4[i], w = w4[i];
    oacc += a.x * w.x + a.y * w.y + a.z * w.z + a.w * w.w;
  }
  size_t oidx = (size_t)outOff + ((size_t)b * 200 + n) * kE + tid;
  if (isbf) ((__hip_bfloat16*)out)[oidx] = __float2bfloat16(oacc);
  else ((float*)out)[oidx] = oacc;
}

}  // namespace

extern "C" void kernel_launch(void* const* d_in, const int* in_sizes, int n_in,
                              void* d_out, int out_size, void* d_ws, size_t ws_size,
                              hipStream_t stream) {
  if (ws_size < WS_NEED) return;  // output stays zero -> loud failure
  const unsigned char* mask = (const unsigned char*)d_in[2];

  float* ws = (float*)d_ws;
  _Float16* hb = (_Float16*)(ws + F32_END);
  int* flags = (int*)(ws + FLAGS);

  detect_kernel<<<dim3(1), 64, 0, stream>>>((const unsigned short*)d_in[0], mask, flags);
  cvt_all_kernel<<<dim3((CVT_TOTAL + 255) / 256), 256, 0, stream>>>(
      d_in[0], d_in[1], d_in[3], d_in[4], d_in[5], d_in[6], d_in[7], d_in[8],
      d_in[9], d_in[10], ws, flags);
  pack_beta_kernel<<<dim3(1), 512, 0, stream>>>(ws + L1C, ws + ALPHAC, ws + BETA);
  pack_w1_kernel<<<dim3(8), 256, 0, stream>>>(ws + L1C, ws + BETA, hb + W1PACK);
  pack_l2_kernel<<<dim3(4), 256, 0, stream>>>(ws + L2C, hb + L2PACK);
  qkv_kernel<<<dim3(200, kB), 256, 0, stream>>>(ws + X1C, ws + WQV1C, hb + QH, ws + V1, 0.25f);
  qkv_kernel<<<dim3(200, kB), 256, 0, stream>>>(ws + X2C, ws + WKV2C, hb + KH, ws + V2, 1.0f);
  mixed_mfma_kernel<<<dim3(13, 13, kB), 64, 0, stream>>>(
      hb + QH, hb + KH, ws + COSTC, hb + W1PACK, hb + L2PACK,
      hb + MIXED, hb + MIXEDT);
  combine_kernel<<<dim3(200, kB), 256, 0, stream>>>(
      hb + MIXED, mask, 200, 1, ws + V2, ws + O1WC, d_out, 0, flags);
  combine_kernel<<<dim3(200, kB), 256, 0, stream>>>(
      hb + MIXEDT, mask, 1, 200, ws + V1, ws + O2WC, d_out, 409600, flags);
}

// Round 6
// 256.838 us; speedup vs baseline: 3.8408x; 2.0670x over previous
//
#include <hip/hip_runtime.h>
#include <hip/hip_bf16.h>
#include <math.h>

// EfficientMixedScoreMultiHeadAttentionLayer — round 6: QKV as MFMA GEMM
// (round-5 profile: qkv_kernel 2x160us latency-bound on 1KB-strided weight
// loads, VALUBusy 5%). Rest identical to round 5 (passed, absmax 0.0039).
// B=8, R=C=200, E=256, H=16, D=16, MS_HID=32, SDIMS=2.

namespace {
constexpr int kB = 8, kR = 200, kC = 200, kE = 256, kH = 16;
constexpr float kNEG = -1e9f;
constexpr float kCLIP = 10.f;

typedef _Float16 f16x8 __attribute__((ext_vector_type(8)));
typedef _Float16 f16x4 __attribute__((ext_vector_type(4)));
typedef float f32x4 __attribute__((ext_vector_type(4)));
typedef unsigned int u32;

// ---- ws layout (f32 element offsets; cvt_all relies on 0..9 being contiguous)
constexpr int X1C = 0;
constexpr int X2C = 409600;
constexpr int COSTC = 819200;
constexpr int WQV1C = 1139200;
constexpr int WKV2C = 1270272;
constexpr int L1C = 1401344;
constexpr int L2C = 1417728;
constexpr int ALPHAC = 1425920;
constexpr int O1WC = 1425936;
constexpr int O2WC = 1491472;
constexpr int CVT_TOTAL = 1557008;
constexpr int V1 = 1557008;
constexpr int V2 = 1966608;
constexpr int BETA = 2376208;
constexpr int FLAGS = 2376720;        // 16 ints
constexpr int F32_END = 2376736;
// f16 element offsets from h base
constexpr int QH = 0;
constexpr int KH = 409600;
constexpr int W1PACK = 819200;        // 32 tiles x 64 lanes x 8
constexpr int L2PACK = 835584;        // 16 steps x 64 lanes x 8
constexpr int MIXED = 843776;         // 5,120,000
constexpr int MIXEDT = 5963776;       // 5,120,000
constexpr int X1H = 11083776;         // 409600
constexpr int X2H = 11493376;         // 409600
constexpr int WQH = 11902976;         // 131072
constexpr int WKH = 12034048;         // 131072
constexpr size_t F16_END = 12165120;
constexpr size_t WS_NEED = (size_t)F32_END * 4 + F16_END * 2;  // 33,837,184 B

__device__ inline _Float16 f2h(float v) { return (_Float16)v; }
__device__ inline u32 pack2(float lo, float hi) {
  return (u32)__builtin_bit_cast(unsigned short, (_Float16)lo) |
         ((u32)__builtin_bit_cast(unsigned short, (_Float16)hi) << 16);
}

__global__ void detect_kernel(const unsigned short* x1h, const unsigned char* mb,
                              int* flags) {
  int l = threadIdx.x;  // 64
  int bad = 0;
  for (int i = l; i < 256; i += 64) {
    float f = __uint_as_float(((u32)x1h[i]) << 16);
    if (!(fabsf(f) <= 1000.f)) bad = 1;  // catches NaN/inf too
  }
  unsigned long long vb = __ballot(bad);
  int nz = 0;
  for (int i = l; i < 512; i += 64)
    if ((i & 3) && mb[i]) nz = 1;
  unsigned long long vn = __ballot(nz);
  if (l == 0) {
    flags[0] = vb ? 0 : 1;  // 1 => float tensors are bf16
    flags[1] = vn ? 1 : 4;  // mask element byte size
  }
}

__global__ __launch_bounds__(256) void cvt_all_kernel(
    const void* s0, const void* s1, const void* s2, const void* s3,
    const void* s4, const void* s5, const void* s6, const void* s7,
    const void* s8, const void* s9, float* __restrict__ ws,
    const int* __restrict__ flags) {
  int i = blockIdx.x * 256 + threadIdx.x;
  if (i >= CVT_TOTAL) return;
  const void* src;
  int off;
  if (i < COSTC) {
    if (i < X2C) { src = s0; off = i; }
    else { src = s1; off = i - X2C; }
  } else if (i < WKV2C) {
    if (i < WQV1C) { src = s2; off = i - COSTC; }
    else { src = s3; off = i - WQV1C; }
  } else if (i < L2C) {
    if (i < L1C) { src = s4; off = i - WKV2C; }
    else { src = s5; off = i - L1C; }
  } else if (i < O1WC) {
    if (i < ALPHAC) { src = s6; off = i - L2C; }
    else { src = s7; off = i - ALPHAC; }
  } else {
    if (i < O2WC) { src = s8; off = i - O1WC; }
    else { src = s9; off = i - O2WC; }
  }
  float v = flags[0] ? __bfloat162float(((const __hip_bfloat16*)src)[off])
                     : ((const float*)src)[off];
  ws[i] = v;
}

__global__ __launch_bounds__(256) void cvt16_kernel(const float* __restrict__ src,
                                                    _Float16* __restrict__ dst, int n) {
  int i = blockIdx.x * 256 + threadIdx.x;
  if (i < n) dst[i] = (_Float16)src[i];
}

__global__ __launch_bounds__(512) void pack_beta_kernel(const float* __restrict__ L1,
                                                        const float* __restrict__ alpha,
                                                        float* __restrict__ beta) {
  int j = threadIdx.x;  // 512
  float acc = 0.f;
#pragma unroll
  for (int h = 0; h < kH; ++h) acc += L1[j * 32 + 2 * h + 1] * alpha[h];
  beta[j] = acc;
}

__global__ __launch_bounds__(256) void pack_w1_kernel(const float* __restrict__ L1,
                                                      const float* __restrict__ beta,
                                                      _Float16* __restrict__ w1pack) {
  int idx = blockIdx.x * 256 + threadIdx.x;  // 2048 = 32 tiles x 64 lanes
  if (idx >= 2048) return;
  int tau = idx >> 6, l = idx & 63;
  int rho = l & 15, gg = l >> 4;
  int k2 = tau >> 1, m = tau & 1;
  int u = k2 * 32 + 8 * (rho >> 2) + 4 * m + (rho & 3);
#pragma unroll
  for (int j = 0; j < 8; ++j) {
    int feat = 8 * gg + j;
    float v = (feat < 16) ? L1[u * 32 + 2 * feat] : (feat == 16 ? beta[u] : 0.f);
    w1pack[idx * 8 + j] = f2h(v);
  }
}

__global__ __launch_bounds__(256) void pack_l2_kernel(const float* __restrict__ L2,
                                                      _Float16* __restrict__ l2pack) {
  int idx = blockIdx.x * 256 + threadIdx.x;  // 1024 = 16 steps x 64 lanes
  if (idx >= 1024) return;
  int k2 = idx >> 6, l = idx & 63;
  int head = l & 15, gg = l >> 4;
#pragma unroll
  for (int j = 0; j < 8; ++j)
    l2pack[idx * 8 + j] = f2h(L2[head * 512 + k2 * 32 + 8 * gg + j]);
}

// ---- QKV as MFMA GEMM: out = x(1600x256) @ W^T(256x512) -------------------
// grid (8, 100), block 256 (4 waves). Wave w: 16x16 output tile at
// rows blockIdx.y*16, cols blockIdx.x*64 + w*16. K=256 in 8 MFMA steps.
// cols 0..255 -> q/k channel (scaled, f16, [b][h][row][d]); 256..511 -> v f32.
__global__ __launch_bounds__(256) void qkv_gemm_kernel(
    const _Float16* __restrict__ x16,   // [1600][256]
    const _Float16* __restrict__ w16,   // [512][256]
    _Float16* __restrict__ oqk,         // [b][h][row][16]
    float* __restrict__ ov,             // [1600][256]
    float scale) {
  const int l = threadIdx.x & 63;
  const int w = threadIdx.x >> 6;
  const int m0 = blockIdx.y * 16;
  const int c0 = blockIdx.x * 64 + w * 16;
  const int arow = m0 + (l & 15);
  const int bcol = c0 + (l & 15);
  const int kb = (l >> 4) * 8;
  const f16x8* ap = reinterpret_cast<const f16x8*>(x16 + (size_t)arow * 256 + kb);
  const f16x8* bp = reinterpret_cast<const f16x8*>(w16 + (size_t)bcol * 256 + kb);
  f32x4 acc = {0.f, 0.f, 0.f, 0.f};
#pragma unroll
  for (int s = 0; s < 8; ++s)
    acc = __builtin_amdgcn_mfma_f32_16x16x32_f16(ap[s * 4], bp[s * 4], acc, 0, 0, 0);
#pragma unroll
  for (int t = 0; t < 4; ++t) {
    int rr = m0 + (l >> 4) * 4 + t;
    int cc = c0 + (l & 15);
    if (cc < 256) {
      int b = rr / 200, r = rr - b * 200;
      oqk[((b * 16 + (cc >> 4)) * 200 + r) * 16 + (cc & 15)] = f2h(scale * acc[t]);
    } else {
      ov[(size_t)rr * 256 + (cc - 256)] = acc[t];
    }
  }
}

// ---- the MFMA mixed kernel: 1 wave/block, 16r x 16c tile --------------------
__global__ __launch_bounds__(64) void mixed_mfma_kernel(
    const _Float16* __restrict__ qh, const _Float16* __restrict__ kh,
    const float* __restrict__ costc,
    const _Float16* __restrict__ w1pack, const _Float16* __restrict__ l2pack,
    _Float16* __restrict__ mixed, _Float16* __restrict__ mixedT) {
  __shared__ _Float16 scores[4096];           // [r16][p16][f16], XOR-swizzled
  __shared__ _Float16 mixtile[16 * 16 * 20];  // [h][c][r pad 20]

  const int l = threadIdx.x;
  const int p = l & 15;   // pair / col
  const int g = l >> 4;   // lane group
  const int b = blockIdx.z;
  const int r0 = blockIdx.y * 16, c0 = blockIdx.x * 16;
  const f32x4 fzero = {0.f, 0.f, 0.f, 0.f};
  const f16x8 hzero = {0, 0, 0, 0, 0, 0, 0, 0};

  // preload packed weight fragments (192 VGPRs)
  f16x8 w1f[32], l2f[16];
  {
    const f16x8* wp = reinterpret_cast<const f16x8*>(w1pack) + l;
#pragma unroll
    for (int t = 0; t < 32; ++t) w1f[t] = wp[t * 64];
    const f16x8* lp = reinterpret_cast<const f16x8*>(l2pack) + l;
#pragma unroll
    for (int t = 0; t < 16; ++t) l2f[t] = lp[t * 64];
  }

  // ---- QK phase: dot_h for the whole 16x16 tile, staged to scores LDS
  int qrow = r0 + p; if (qrow > 199) qrow = 199;
  int krow = c0 + p; if (krow > 199) krow = 199;
  for (int hc = 0; hc < 4; ++hc) {
    f32x4 acc[4];
#pragma unroll
    for (int i = 0; i < 4; ++i) {
      int h = hc * 4 + i;
      f16x8 qf = hzero, kf = hzero;
      if (g < 2) {
        qf = *reinterpret_cast<const f16x8*>(qh + ((b * 16 + h) * 200 + qrow) * 16 + 8 * g);
        kf = *reinterpret_cast<const f16x8*>(kh + ((b * 16 + h) * 200 + krow) * 16 + 8 * g);
      }
      acc[i] = __builtin_amdgcn_mfma_f32_16x16x32_f16(qf, kf, fzero, 0, 0, 0);
    }
    // write 4 heads (2 packed pairs); cell (rho=4g+t, p, f=h), swz on byte addr
#pragma unroll
    for (int pr = 0; pr < 2; ++pr) {
      int h = hc * 4 + pr * 2;
#pragma unroll
      for (int t = 0; t < 4; ++t) {
        u32 pk = pack2(acc[pr * 2][t], acc[pr * 2 + 1][t]);
        u32 a = (u32)((4 * g + t) * 512 + p * 32 + h * 2) ^ (((p >> 2) & 3) << 4);
        *reinterpret_cast<u32*>(reinterpret_cast<char*>(scores) + a) = pk;
      }
    }
  }
  __syncthreads();

  // ---- main loop: per r-subtile, GEMM1 (x2) -> relu/pack -> GEMM2
  for (int r = 0; r < 16; ++r) {
    u32 a = (u32)(r * 512 + p * 32 + (g & 1) * 16) ^ (((p >> 2) & 3) << 4);
    f16x8 sfrag = *reinterpret_cast<const f16x8*>(reinterpret_cast<char*>(scores) + a);
    int rr = r0 + r; if (rr > 199) rr = 199;
    int cc = c0 + p; if (cc > 199) cc = 199;
    float cv = costc[(b * 200 + rr) * 200 + cc];
    f16x8 bfrag;
    if (g < 2) bfrag = sfrag;
    else if (g == 2) { bfrag = hzero; bfrag[0] = f2h(cv); }  // k-slot 16 = cost
    else bfrag = hzero;

    f32x4 macc = fzero;
#pragma unroll
    for (int k2 = 0; k2 < 16; ++k2) {
      f32x4 h0 = __builtin_amdgcn_mfma_f32_16x16x32_f16(w1f[2 * k2], bfrag, fzero, 0, 0, 0);
      f32x4 h1 = __builtin_amdgcn_mfma_f32_16x16x32_f16(w1f[2 * k2 + 1], bfrag, fzero, 0, 0, 0);
      f16x8 pf;
      pf[0] = f2h(fmaxf(h0[0], 0.f));
      pf[1] = f2h(fmaxf(h0[1], 0.f));
      pf[2] = f2h(fmaxf(h0[2], 0.f));
      pf[3] = f2h(fmaxf(h0[3], 0.f));
      pf[4] = f2h(fmaxf(h1[0], 0.f));
      pf[5] = f2h(fmaxf(h1[1], 0.f));
      pf[6] = f2h(fmaxf(h1[2], 0.f));
      pf[7] = f2h(fmaxf(h1[3], 0.f));
      macc = __builtin_amdgcn_mfma_f32_16x16x32_f16(l2f[k2], pf, macc, 0, 0, 0);
    }
    // macc: lane -> mixed^T[head=4g+t][pair=p] for this r
    bool vr = (r0 + r) < 200, vc = (c0 + p) < 200;
#pragma unroll
    for (int t = 0; t < 4; ++t) {
      int h = 4 * g + t;
      _Float16 mb = f2h(macc[t]);
      if (vr && vc)
        mixed[((size_t)(b * 16 + h) * 200 + (r0 + r)) * 200 + (c0 + p)] = mb;
      mixtile[(h * 16 + p) * 20 + r] = mb;
    }
  }
  __syncthreads();

  // ---- coalesced mixedT stores: [bh][c][r], 16 r's per (h,c)
#pragma unroll
  for (int i = 0; i < 4; ++i) {
    int idx = i * 64 + l, h = idx >> 4, c = idx & 15;
    if ((c0 + c) < 200) {
      const _Float16* src = &mixtile[(h * 16 + c) * 20];
      f16x4 a0 = *reinterpret_cast<const f16x4*>(src);
      f16x4 a1 = *reinterpret_cast<const f16x4*>(src + 4);
      f16x4 a2 = *reinterpret_cast<const f16x4*>(src + 8);
      f16x4 a3 = *reinterpret_cast<const f16x4*>(src + 12);
      _Float16* dst = mixedT + ((size_t)(b * 16 + h) * 200 + (c0 + c)) * 200 + r0;
      *reinterpret_cast<f16x4*>(dst) = a0;
      *(reinterpret_cast<f16x4*>(dst) + 1) = a1;
      if (r0 + 15 < 200) {
        *(reinterpret_cast<f16x4*>(dst) + 2) = a2;
        *(reinterpret_cast<f16x4*>(dst) + 3) = a3;
      }
    }
  }
}

__global__ __launch_bounds__(256) void combine_kernel(
    const _Float16* __restrict__ logits,     // (B,H,200,200), softmax last dim
    const unsigned char* __restrict__ mask,  // (B,200,200), elt size flags[1]
    int sn, int sm,                          // mask elt idx = b*40000+n*sn+m*sm
    const float* __restrict__ v,             // (B,200,256)
    const float* __restrict__ Wout,          // (256,256)
    void* __restrict__ out, int outOff, const int* __restrict__ flags) {
  __shared__ float wsm[kH][kC];
  __shared__ float pre[kE];
  int n = blockIdx.x, b = blockIdx.y, tid = threadIdx.x;
  int gg = tid >> 4, ll = tid & 15;
  int isbf = flags[0];
  int ms = flags[1];

  const _Float16* lg = logits + (((size_t)b * kH + gg) * 200 + n) * 200;
  const unsigned char* mk = mask + ((size_t)b * 40000 + (size_t)n * sn) * ms;

  float mx = kNEG;
  for (int m = ll; m < 200; m += 16) {
    bool masked = mk[(size_t)m * sm * ms] != 0;
    float x = masked ? kNEG : tanhf((float)lg[m]) * kCLIP;
    wsm[gg][m] = x;
    mx = fmaxf(mx, x);
  }
#pragma unroll
  for (int o = 8; o >= 1; o >>= 1) mx = fmaxf(mx, __shfl_xor(mx, o, 16));
  float se = 0.f;
  for (int m = ll; m < 200; m += 16) {
    float e = expf(wsm[gg][m] - mx);
    wsm[gg][m] = e;
    se += e;
  }
#pragma unroll
  for (int o = 8; o >= 1; o >>= 1) se += __shfl_xor(se, o, 16);
  float inv = (mx <= -1e8f) ? 0.f : 1.f / se;
  for (int m = ll; m < 200; m += 16) wsm[gg][m] *= inv;
  __syncthreads();

  float acc = 0.f;
  const float* vp = v + (size_t)b * 200 * kE + tid;
#pragma unroll 4
  for (int m = 0; m < 200; ++m) acc += wsm[gg][m] * vp[(size_t)m * kE];
  pre[tid] = acc;
  __syncthreads();

  const float4* p4 = reinterpret_cast<const float4*>(pre);
  const float4* w4 = reinterpret_cast<const float4*>(Wout + (size_t)tid * kE);
  float oacc = 0.f;
#pragma unroll 8
  for (int i = 0; i < kE / 4; ++i) {
    float4 a = p4[i], w = w4[i];
    oacc += a.x * w.x + a.y * w.y + a.z * w.z + a.w * w.w;
  }
  size_t oidx = (size_t)outOff + ((size_t)b * 200 + n) * kE + tid;
  if (isbf) ((__hip_bfloat16*)out)[oidx] = __float2bfloat16(oacc);
  else ((float*)out)[oidx] = oacc;
}

}  // namespace

extern "C" void kernel_launch(void* const* d_in, const int* in_sizes, int n_in,
                              void* d_out, int out_size, void* d_ws, size_t ws_size,
                              hipStream_t stream) {
  if (ws_size < WS_NEED) return;  // output stays zero -> loud failure
  const unsigned char* mask = (const unsigned char*)d_in[2];

  float* ws = (float*)d_ws;
  _Float16* hb = (_Float16*)(ws + F32_END);
  int* flags = (int*)(ws + FLAGS);

  detect_kernel<<<dim3(1), 64, 0, stream>>>((const unsigned short*)d_in[0], mask, flags);
  cvt_all_kernel<<<dim3((CVT_TOTAL + 255) / 256), 256, 0, stream>>>(
      d_in[0], d_in[1], d_in[3], d_in[4], d_in[5], d_in[6], d_in[7], d_in[8],
      d_in[9], d_in[10], ws, flags);
  cvt16_kernel<<<dim3(1600), 256, 0, stream>>>(ws + X1C, hb + X1H, 409600);
  cvt16_kernel<<<dim3(1600), 256, 0, stream>>>(ws + X2C, hb + X2H, 409600);
  cvt16_kernel<<<dim3(512), 256, 0, stream>>>(ws + WQV1C, hb + WQH, 131072);
  cvt16_kernel<<<dim3(512), 256, 0, stream>>>(ws + WKV2C, hb + WKH, 131072);
  pack_beta_kernel<<<dim3(1), 512, 0, stream>>>(ws + L1C, ws + ALPHAC, ws + BETA);
  pack_w1_kernel<<<dim3(8), 256, 0, stream>>>(ws + L1C, ws + BETA, hb + W1PACK);
  pack_l2_kernel<<<dim3(4), 256, 0, stream>>>(ws + L2C, hb + L2PACK);
  qkv_gemm_kernel<<<dim3(8, 100), 256, 0, stream>>>(hb + X1H, hb + WQH, hb + QH,
                                                    ws + V1, 0.25f);
  qkv_gemm_kernel<<<dim3(8, 100), 256, 0, stream>>>(hb + X2H, hb + WKH, hb + KH,
                                                    ws + V2, 1.0f);
  mixed_mfma_kernel<<<dim3(13, 13, kB), 64, 0, stream>>>(
      hb + QH, hb + KH, ws + COSTC, hb + W1PACK, hb + L2PACK,
      hb + MIXED, hb + MIXEDT);
  combine_kernel<<<dim3(200, kB), 256, 0, stream>>>(
      hb + MIXED, mask, 200, 1, ws + V2, ws + O1WC, d_out, 0, flags);
  combine_kernel<<<dim3(200, kB), 256, 0, stream>>>(
      hb + MIXEDT, mask, 1, 200, ws + V1, ws + O2WC, d_out, 409600, flags);
}

// Round 7
// 165.110 us; speedup vs baseline: 5.9746x; 1.5556x over previous
//
#include <hip/hip_runtime.h>
#include <hip/hip_bf16.h>
#include <math.h>

// EfficientMixedScoreMultiHeadAttentionLayer — round 7: MFMA-fused combine.
// Round-6 profile: combine_kernel 2x86.8us (VALU 18%, Mfma 0, latency-bound
// serial w.v loop + 10M tanh). Replaced by fused_combine (reg softmax + MFMA
// P@vT per (b,h,rtile)) + out_gemm (wv @ Wout^T, qkv_gemm structure).
// B=8, R=C=200, E=256, H=16, D=16, MS_HID=32, SDIMS=2.

namespace {
constexpr int kB = 8, kH = 16;
constexpr float kNEG = -1e9f;
constexpr float kCLIP = 10.f;

typedef _Float16 f16x8 __attribute__((ext_vector_type(8)));
typedef _Float16 f16x4 __attribute__((ext_vector_type(4)));
typedef float f32x4 __attribute__((ext_vector_type(4)));
typedef unsigned int u32;

// ---- ws layout (f32 element offsets; cvt_all relies on 0..9 being contiguous)
constexpr int X1C = 0;
constexpr int X2C = 409600;
constexpr int COSTC = 819200;
constexpr int WQV1C = 1139200;
constexpr int WKV2C = 1270272;
constexpr int L1C = 1401344;
constexpr int L2C = 1417728;
constexpr int ALPHAC = 1425920;
constexpr int O1WC = 1425936;
constexpr int O2WC = 1491472;
constexpr int CVT_TOTAL = 1557008;
constexpr int BETA = 1557008;
constexpr int FLAGS = 1557520;        // 16 ints
constexpr int F32_END = 1557536;
// f16 element offsets from h base
constexpr int QH = 0;
constexpr int KH = 409600;
constexpr int W1PACK = 819200;        // 32 tiles x 64 lanes x 8
constexpr int L2PACK = 835584;        // 16 steps x 64 lanes x 8
constexpr int MIXED = 843776;         // 5,120,000
constexpr int MIXEDT = 5963776;       // 5,120,000
constexpr int X1H = 11083776;         // 409600
constexpr int X2H = 11493376;         // 409600
constexpr int WQH = 11902976;         // 131072
constexpr int WKH = 12034048;         // 131072
constexpr int VT1 = 12165120;         // 2048 rows x 224  (v from x1, transposed)
constexpr int VT2 = 12623872;         // 2048 rows x 224  (v from x2)
constexpr int WV1 = 13082624;         // 409600  [b][r][256]
constexpr int WV2 = 13492224;         // 409600  [b][c][256]
constexpr int O1H = 13901824;         // 65536
constexpr int O2H = 13967360;         // 65536
constexpr size_t F16_END = 14032896;
constexpr size_t WS_NEED = (size_t)F32_END * 4 + F16_END * 2;  // 34,295,936 B

__device__ inline _Float16 f2h(float v) { return (_Float16)v; }
__device__ inline u32 pack2(float lo, float hi) {
  return (u32)__builtin_bit_cast(unsigned short, (_Float16)lo) |
         ((u32)__builtin_bit_cast(unsigned short, (_Float16)hi) << 16);
}

__global__ void detect_kernel(const unsigned short* x1h, const unsigned char* mb,
                              int* flags) {
  int l = threadIdx.x;  // 64
  int bad = 0;
  for (int i = l; i < 256; i += 64) {
    float f = __uint_as_float(((u32)x1h[i]) << 16);
    if (!(fabsf(f) <= 1000.f)) bad = 1;  // catches NaN/inf too
  }
  unsigned long long vb = __ballot(bad);
  int nz = 0;
  for (int i = l; i < 512; i += 64)
    if ((i & 3) && mb[i]) nz = 1;
  unsigned long long vn = __ballot(nz);
  if (l == 0) {
    flags[0] = vb ? 0 : 1;  // 1 => float tensors are bf16
    flags[1] = vn ? 1 : 4;  // mask element byte size
  }
}

__global__ __launch_bounds__(256) void cvt_all_kernel(
    const void* s0, const void* s1, const void* s2, const void* s3,
    const void* s4, const void* s5, const void* s6, const void* s7,
    const void* s8, const void* s9, float* __restrict__ ws,
    const int* __restrict__ flags) {
  int i = blockIdx.x * 256 + threadIdx.x;
  if (i >= CVT_TOTAL) return;
  const void* src;
  int off;
  if (i < COSTC) {
    if (i < X2C) { src = s0; off = i; }
    else { src = s1; off = i - X2C; }
  } else if (i < WKV2C) {
    if (i < WQV1C) { src = s2; off = i - COSTC; }
    else { src = s3; off = i - WQV1C; }
  } else if (i < L2C) {
    if (i < L1C) { src = s4; off = i - WKV2C; }
    else { src = s5; off = i - L1C; }
  } else if (i < O1WC) {
    if (i < ALPHAC) { src = s6; off = i - L2C; }
    else { src = s7; off = i - ALPHAC; }
  } else {
    if (i < O2WC) { src = s8; off = i - O1WC; }
    else { src = s9; off = i - O2WC; }
  }
  float v = flags[0] ? __bfloat162float(((const __hip_bfloat16*)src)[off])
                     : ((const float*)src)[off];
  ws[i] = v;
}

__global__ __launch_bounds__(256) void cvt16_kernel(const float* __restrict__ src,
                                                    _Float16* __restrict__ dst, int n) {
  int i = blockIdx.x * 256 + threadIdx.x;
  if (i < n) dst[i] = (_Float16)src[i];
}

__global__ __launch_bounds__(256) void zpad_vt_kernel(_Float16* __restrict__ vt1,
                                                      _Float16* __restrict__ vt2) {
  int i = blockIdx.x * 256 + threadIdx.x;  // 49152 = 2048 rows x 24 pad
  if (i >= 49152) return;
  int row = i / 24, c = 200 + i % 24;
  vt1[row * 224 + c] = (_Float16)0.f;
  vt2[row * 224 + c] = (_Float16)0.f;
}

__global__ __launch_bounds__(512) void pack_beta_kernel(const float* __restrict__ L1,
                                                        const float* __restrict__ alpha,
                                                        float* __restrict__ beta) {
  int j = threadIdx.x;  // 512
  float acc = 0.f;
#pragma unroll
  for (int h = 0; h < kH; ++h) acc += L1[j * 32 + 2 * h + 1] * alpha[h];
  beta[j] = acc;
}

__global__ __launch_bounds__(256) void pack_w1_kernel(const float* __restrict__ L1,
                                                      const float* __restrict__ beta,
                                                      _Float16* __restrict__ w1pack) {
  int idx = blockIdx.x * 256 + threadIdx.x;  // 2048 = 32 tiles x 64 lanes
  if (idx >= 2048) return;
  int tau = idx >> 6, l = idx & 63;
  int rho = l & 15, gg = l >> 4;
  int k2 = tau >> 1, m = tau & 1;
  int u = k2 * 32 + 8 * (rho >> 2) + 4 * m + (rho & 3);
#pragma unroll
  for (int j = 0; j < 8; ++j) {
    int feat = 8 * gg + j;
    float v = (feat < 16) ? L1[u * 32 + 2 * feat] : (feat == 16 ? beta[u] : 0.f);
    w1pack[idx * 8 + j] = f2h(v);
  }
}

__global__ __launch_bounds__(256) void pack_l2_kernel(const float* __restrict__ L2,
                                                      _Float16* __restrict__ l2pack) {
  int idx = blockIdx.x * 256 + threadIdx.x;  // 1024 = 16 steps x 64 lanes
  if (idx >= 1024) return;
  int k2 = idx >> 6, l = idx & 63;
  int head = l & 15, gg = l >> 4;
#pragma unroll
  for (int j = 0; j < 8; ++j)
    l2pack[idx * 8 + j] = f2h(L2[head * 512 + k2 * 32 + 8 * gg + j]);
}

// ---- QKV as MFMA GEMM: out = x(1600x256) @ W^T(256x512) -------------------
// grid (8, 100), block 256 (4 waves). Wave w: 16x16 tile at rows blockIdx.y*16,
// cols blockIdx.x*64 + w*16. cols 0..255 -> q/k (scaled f16 [b][h][row][16]);
// 256..511 -> v, stored TRANSPOSED f16 vT[(b*16+h)*16+d][224] (K-padded).
__global__ __launch_bounds__(256) void qkv_gemm_kernel(
    const _Float16* __restrict__ x16,   // [1600][256]
    const _Float16* __restrict__ w16,   // [512][256]
    _Float16* __restrict__ oqk,         // [b][h][row][16]
    _Float16* __restrict__ vt,          // [2048][224]
    float scale) {
  const int l = threadIdx.x & 63;
  const int w = threadIdx.x >> 6;
  const int m0 = blockIdx.y * 16;
  const int c0 = blockIdx.x * 64 + w * 16;
  const int arow = m0 + (l & 15);
  const int bcol = c0 + (l & 15);
  const int kb = (l >> 4) * 8;
  const f16x8* ap = reinterpret_cast<const f16x8*>(x16 + (size_t)arow * 256 + kb);
  const f16x8* bp = reinterpret_cast<const f16x8*>(w16 + (size_t)bcol * 256 + kb);
  f32x4 acc = {0.f, 0.f, 0.f, 0.f};
#pragma unroll
  for (int s = 0; s < 8; ++s)
    acc = __builtin_amdgcn_mfma_f32_16x16x32_f16(ap[s * 4], bp[s * 4], acc, 0, 0, 0);
#pragma unroll
  for (int t = 0; t < 4; ++t) {
    int rr = m0 + (l >> 4) * 4 + t;
    int cc = c0 + (l & 15);
    int b = rr / 200, r = rr - b * 200;
    if (cc < 256) {
      oqk[((b * 16 + (cc >> 4)) * 200 + r) * 16 + (cc & 15)] = f2h(scale * acc[t]);
    } else {
      int h = (cc - 256) >> 4, d = (cc - 256) & 15;
      vt[(size_t)((b * 16 + h) * 16 + d) * 224 + r] = f2h(acc[t]);
    }
  }
}

// ---- the MFMA mixed kernel: 1 wave/block, 16r x 16c tile --------------------
__global__ __launch_bounds__(64) void mixed_mfma_kernel(
    const _Float16* __restrict__ qh, const _Float16* __restrict__ kh,
    const float* __restrict__ costc,
    const _Float16* __restrict__ w1pack, const _Float16* __restrict__ l2pack,
    _Float16* __restrict__ mixed, _Float16* __restrict__ mixedT) {
  __shared__ _Float16 scores[4096];           // [r16][p16][f16], XOR-swizzled
  __shared__ _Float16 mixtile[16 * 16 * 20];  // [h][c][r pad 20]

  const int l = threadIdx.x;
  const int p = l & 15;   // pair / col
  const int g = l >> 4;   // lane group
  const int b = blockIdx.z;
  const int r0 = blockIdx.y * 16, c0 = blockIdx.x * 16;
  const f32x4 fzero = {0.f, 0.f, 0.f, 0.f};
  const f16x8 hzero = {0, 0, 0, 0, 0, 0, 0, 0};

  // preload packed weight fragments (192 VGPRs)
  f16x8 w1f[32], l2f[16];
  {
    const f16x8* wp = reinterpret_cast<const f16x8*>(w1pack) + l;
#pragma unroll
    for (int t = 0; t < 32; ++t) w1f[t] = wp[t * 64];
    const f16x8* lp = reinterpret_cast<const f16x8*>(l2pack) + l;
#pragma unroll
    for (int t = 0; t < 16; ++t) l2f[t] = lp[t * 64];
  }

  // ---- QK phase: dot_h for the whole 16x16 tile, staged to scores LDS
  int qrow = r0 + p; if (qrow > 199) qrow = 199;
  int krow = c0 + p; if (krow > 199) krow = 199;
  for (int hc = 0; hc < 4; ++hc) {
    f32x4 acc[4];
#pragma unroll
    for (int i = 0; i < 4; ++i) {
      int h = hc * 4 + i;
      f16x8 qf = hzero, kf = hzero;
      if (g < 2) {
        qf = *reinterpret_cast<const f16x8*>(qh + ((b * 16 + h) * 200 + qrow) * 16 + 8 * g);
        kf = *reinterpret_cast<const f16x8*>(kh + ((b * 16 + h) * 200 + krow) * 16 + 8 * g);
      }
      acc[i] = __builtin_amdgcn_mfma_f32_16x16x32_f16(qf, kf, fzero, 0, 0, 0);
    }
    // write 4 heads (2 packed pairs); cell (rho=4g+t, p, f=h), swz on byte addr
#pragma unroll
    for (int pr = 0; pr < 2; ++pr) {
      int h = hc * 4 + pr * 2;
#pragma unroll
      for (int t = 0; t < 4; ++t) {
        u32 pk = pack2(acc[pr * 2][t], acc[pr * 2 + 1][t]);
        u32 a = (u32)((4 * g + t) * 512 + p * 32 + h * 2) ^ (((p >> 2) & 3) << 4);
        *reinterpret_cast<u32*>(reinterpret_cast<char*>(scores) + a) = pk;
      }
    }
  }
  __syncthreads();

  // ---- main loop: per r-subtile, GEMM1 (x2) -> relu/pack -> GEMM2
  for (int r = 0; r < 16; ++r) {
    u32 a = (u32)(r * 512 + p * 32 + (g & 1) * 16) ^ (((p >> 2) & 3) << 4);
    f16x8 sfrag = *reinterpret_cast<const f16x8*>(reinterpret_cast<char*>(scores) + a);
    int rr = r0 + r; if (rr > 199) rr = 199;
    int cc = c0 + p; if (cc > 199) cc = 199;
    float cv = costc[(b * 200 + rr) * 200 + cc];
    f16x8 bfrag;
    if (g < 2) bfrag = sfrag;
    else if (g == 2) { bfrag = hzero; bfrag[0] = f2h(cv); }  // k-slot 16 = cost
    else bfrag = hzero;

    f32x4 macc = fzero;
#pragma unroll
    for (int k2 = 0; k2 < 16; ++k2) {
      f32x4 h0 = __builtin_amdgcn_mfma_f32_16x16x32_f16(w1f[2 * k2], bfrag, fzero, 0, 0, 0);
      f32x4 h1 = __builtin_amdgcn_mfma_f32_16x16x32_f16(w1f[2 * k2 + 1], bfrag, fzero, 0, 0, 0);
      f16x8 pf;
      pf[0] = f2h(fmaxf(h0[0], 0.f));
      pf[1] = f2h(fmaxf(h0[1], 0.f));
      pf[2] = f2h(fmaxf(h0[2], 0.f));
      pf[3] = f2h(fmaxf(h0[3], 0.f));
      pf[4] = f2h(fmaxf(h1[0], 0.f));
      pf[5] = f2h(fmaxf(h1[1], 0.f));
      pf[6] = f2h(fmaxf(h1[2], 0.f));
      pf[7] = f2h(fmaxf(h1[3], 0.f));
      macc = __builtin_amdgcn_mfma_f32_16x16x32_f16(l2f[k2], pf, macc, 0, 0, 0);
    }
    // macc: lane -> mixed^T[head=4g+t][pair=p] for this r
    bool vr = (r0 + r) < 200, vc = (c0 + p) < 200;
#pragma unroll
    for (int t = 0; t < 4; ++t) {
      int h = 4 * g + t;
      _Float16 mb = f2h(macc[t]);
      if (vr && vc)
        mixed[((size_t)(b * 16 + h) * 200 + (r0 + r)) * 200 + (c0 + p)] = mb;
      mixtile[(h * 16 + p) * 20 + r] = mb;
    }
  }
  __syncthreads();

  // ---- coalesced mixedT stores: [bh][c][r], 16 r's per (h,c)
#pragma unroll
  for (int i = 0; i < 4; ++i) {
    int idx = i * 64 + l, h = idx >> 4, c = idx & 15;
    if ((c0 + c) < 200) {
      const _Float16* src = &mixtile[(h * 16 + c) * 20];
      f16x4 a0 = *reinterpret_cast<const f16x4*>(src);
      f16x4 a1 = *reinterpret_cast<const f16x4*>(src + 4);
      f16x4 a2 = *reinterpret_cast<const f16x4*>(src + 8);
      f16x4 a3 = *reinterpret_cast<const f16x4*>(src + 12);
      _Float16* dst = mixedT + ((size_t)(b * 16 + h) * 200 + (c0 + c)) * 200 + r0;
      *reinterpret_cast<f16x4*>(dst) = a0;
      *(reinterpret_cast<f16x4*>(dst) + 1) = a1;
      if (r0 + 15 < 200) {
        *(reinterpret_cast<f16x4*>(dst) + 2) = a2;
        *(reinterpret_cast<f16x4*>(dst) + 3) = a3;
      }
    }
  }
}

// ---- fused softmax + P@vT: grid (13 rtile, 16 h, 8 b), 1 wave/block --------
// Per block: 16 rows of softmax(tanh*10, mask) in registers -> P f16 in
// XOR-swizzled LDS [16][256] -> 7 MFMAs vs vT -> wv[b][row][h*16+d] f16.
__global__ __launch_bounds__(64) void fused_combine_kernel(
    const _Float16* __restrict__ logits,     // [bh][n][200]
    const unsigned char* __restrict__ mask,  // elt idx b*40000+n*sn+m*sm
    int sn, int sm,
    const _Float16* __restrict__ vt,         // [bh*16+d][224]
    _Float16* __restrict__ wv,               // [b][n][256]
    const int* __restrict__ flags) {
  __shared__ _Float16 wt[16 * 256];          // rows 512B, XOR-swizzled
  const int l = threadIdx.x;
  const int row = l & 15, grp = l >> 4;
  const int r0 = blockIdx.x * 16;
  const int h = blockIdx.y, b = blockIdx.z;
  const int bh = b * 16 + h;
  const int ms = flags[1];
  int n = r0 + row; if (n > 199) n = 199;
  const _Float16* lg = logits + ((size_t)bh * 200 + n) * 200;
  const unsigned char* mk = mask + ((size_t)b * 40000 + (size_t)n * sn) * ms;

  float xv[7][8];
  float mx = kNEG;
#pragma unroll
  for (int i = 0; i < 7; ++i) {
    int c0 = grp * 8 + i * 32;
    if (c0 < 200) {  // c0 multiple of 8 -> c0+7 <= 199
      f16x8 lv = *reinterpret_cast<const f16x8*>(lg + c0);
#pragma unroll
      for (int j = 0; j < 8; ++j) {
        bool mskd = mk[(size_t)(c0 + j) * sm * ms] != 0;
        float x = mskd ? kNEG : tanhf((float)lv[j]) * kCLIP;
        xv[i][j] = x;
        mx = fmaxf(mx, x);
      }
    } else {
#pragma unroll
      for (int j = 0; j < 8; ++j) xv[i][j] = kNEG;
    }
  }
  mx = fmaxf(mx, __shfl_xor(mx, 16));
  mx = fmaxf(mx, __shfl_xor(mx, 32));
  float se = 0.f;
#pragma unroll
  for (int i = 0; i < 7; ++i)
#pragma unroll
    for (int j = 0; j < 8; ++j) {
      float e = expf(xv[i][j] - mx);
      xv[i][j] = e;
      se += e;
    }
  se += __shfl_xor(se, 16);
  se += __shfl_xor(se, 32);
  float inv = (mx <= -1e8f) ? 0.f : 1.f / se;  // all-masked row -> zero weights
#pragma unroll
  for (int i = 0; i < 7; ++i) {
    int c0 = grp * 8 + i * 32;
    f16x8 pv;
#pragma unroll
    for (int j = 0; j < 8; ++j) pv[j] = f2h(xv[i][j] * inv);
    u32 a = (u32)(row * 512 + c0 * 2) ^ (u32)((row & 7) << 4);
    *reinterpret_cast<f16x8*>(reinterpret_cast<char*>(wt) + a) = pv;
  }
  __syncthreads();

  f32x4 acc = {0.f, 0.f, 0.f, 0.f};
#pragma unroll
  for (int k2 = 0; k2 < 7; ++k2) {
    int kb = k2 * 32 + grp * 8;
    u32 a = (u32)(row * 512 + kb * 2) ^ (u32)((row & 7) << 4);
    f16x8 af = *reinterpret_cast<const f16x8*>(reinterpret_cast<char*>(wt) + a);
    f16x8 bf = *reinterpret_cast<const f16x8*>(vt + (size_t)(bh * 16 + row) * 224 + kb);
    acc = __builtin_amdgcn_mfma_f32_16x16x32_f16(af, bf, acc, 0, 0, 0);
  }
#pragma unroll
  for (int t = 0; t < 4; ++t) {
    int r = r0 + grp * 4 + t;
    if (r < 200)
      wv[((size_t)b * 200 + r) * 256 + h * 16 + row] = f2h(acc[t]);
  }
}

// ---- out = wv(1600x256) @ Wout^T(256x256), dtype-flagged store -------------
__global__ __launch_bounds__(256) void out_gemm_kernel(
    const _Float16* __restrict__ wvh,    // [1600][256]
    const _Float16* __restrict__ wout,   // [256][256]
    void* __restrict__ out, int outOff, const int* __restrict__ flags) {
  const int l = threadIdx.x & 63;
  const int w = threadIdx.x >> 6;
  const int m0 = blockIdx.y * 16;
  const int c0 = blockIdx.x * 64 + w * 16;
  const int arow = m0 + (l & 15);
  const int bcol = c0 + (l & 15);
  const int kb = (l >> 4) * 8;
  const f16x8* ap = reinterpret_cast<const f16x8*>(wvh + (size_t)arow * 256 + kb);
  const f16x8* bp = reinterpret_cast<const f16x8*>(wout + (size_t)bcol * 256 + kb);
  f32x4 acc = {0.f, 0.f, 0.f, 0.f};
#pragma unroll
  for (int s = 0; s < 8; ++s)
    acc = __builtin_amdgcn_mfma_f32_16x16x32_f16(ap[s * 4], bp[s * 4], acc, 0, 0, 0);
  int isbf = flags[0];
#pragma unroll
  for (int t = 0; t < 4; ++t) {
    size_t oidx = (size_t)outOff + (size_t)(m0 + (l >> 4) * 4 + t) * 256 + c0 + (l & 15);
    if (isbf) ((__hip_bfloat16*)out)[oidx] = __float2bfloat16(acc[t]);
    else ((float*)out)[oidx] = acc[t];
  }
}

}  // namespace

extern "C" void kernel_launch(void* const* d_in, const int* in_sizes, int n_in,
                              void* d_out, int out_size, void* d_ws, size_t ws_size,
                              hipStream_t stream) {
  if (ws_size < WS_NEED) return;  // output stays zero -> loud failure
  const unsigned char* mask = (const unsigned char*)d_in[2];

  float* ws = (float*)d_ws;
  _Float16* hb = (_Float16*)(ws + F32_END);
  int* flags = (int*)(ws + FLAGS);

  detect_kernel<<<dim3(1), 64, 0, stream>>>((const unsigned short*)d_in[0], mask, flags);
  cvt_all_kernel<<<dim3((CVT_TOTAL + 255) / 256), 256, 0, stream>>>(
      d_in[0], d_in[1], d_in[3], d_in[4], d_in[5], d_in[6], d_in[7], d_in[8],
      d_in[9], d_in[10], ws, flags);
  cvt16_kernel<<<dim3(1600), 256, 0, stream>>>(ws + X1C, hb + X1H, 409600);
  cvt16_kernel<<<dim3(1600), 256, 0, stream>>>(ws + X2C, hb + X2H, 409600);
  cvt16_kernel<<<dim3(512), 256, 0, stream>>>(ws + WQV1C, hb + WQH, 131072);
  cvt16_kernel<<<dim3(512), 256, 0, stream>>>(ws + WKV2C, hb + WKH, 131072);
  cvt16_kernel<<<dim3(256), 256, 0, stream>>>(ws + O1WC, hb + O1H, 65536);
  cvt16_kernel<<<dim3(256), 256, 0, stream>>>(ws + O2WC, hb + O2H, 65536);
  zpad_vt_kernel<<<dim3(192), 256, 0, stream>>>(hb + VT1, hb + VT2);
  pack_beta_kernel<<<dim3(1), 512, 0, stream>>>(ws + L1C, ws + ALPHAC, ws + BETA);
  pack_w1_kernel<<<dim3(8), 256, 0, stream>>>(ws + L1C, ws + BETA, hb + W1PACK);
  pack_l2_kernel<<<dim3(4), 256, 0, stream>>>(ws + L2C, hb + L2PACK);
  qkv_gemm_kernel<<<dim3(8, 100), 256, 0, stream>>>(hb + X1H, hb + WQH, hb + QH,
                                                    hb + VT1, 0.25f);
  qkv_gemm_kernel<<<dim3(8, 100), 256, 0, stream>>>(hb + X2H, hb + WKH, hb + KH,
                                                    hb + VT2, 1.0f);
  mixed_mfma_kernel<<<dim3(13, 13, kB), 64, 0, stream>>>(
      hb + QH, hb + KH, ws + COSTC, hb + W1PACK, hb + L2PACK,
      hb + MIXED, hb + MIXEDT);
  // dir1: softmax over c of mixed, times v2 (from x2)
  fused_combine_kernel<<<dim3(13, 16, kB), 64, 0, stream>>>(
      hb + MIXED, mask, 200, 1, hb + VT2, hb + WV1, flags);
  // dir2: softmax over r of mixed^T, times v1 (from x1)
  fused_combine_kernel<<<dim3(13, 16, kB), 64, 0, stream>>>(
      hb + MIXEDT, mask, 1, 200, hb + VT1, hb + WV2, flags);
  out_gemm_kernel<<<dim3(4, 100), 256, 0, stream>>>(hb + WV1, hb + O1H, d_out, 0, flags);
  out_gemm_kernel<<<dim3(4, 100), 256, 0, stream>>>(hb + WV2, hb + O2H, d_out, 409600, flags);
}

// Round 9
// 115.789 us; speedup vs baseline: 8.5195x; 1.4259x over previous
//
#include <hip/hip_runtime.h>
#include <hip/hip_bf16.h>
#include <math.h>

// EfficientMixedScoreMultiHeadAttentionLayer — round 9 (= round 8 + pkrtz
// bit_cast fix). vs round 7 (165us): mixed_mfma 4 waves/block + 2-chain ILP +
// pkrtz repack (was 1 wave/block, occ 10%, VALU 35% > Mfma 12%); launches
// 17 -> 8 (cvt16 folded into cvt_all, packs merged, dir-pairs via gridDim.z).
// B=8, R=C=200, E=256, H=16, D=16, MS_HID=32, SDIMS=2.

namespace {
constexpr int kB = 8, kH = 16;
constexpr float kNEG = -1e9f;
constexpr float kCLIP = 10.f;

typedef _Float16 f16x8 __attribute__((ext_vector_type(8)));
typedef _Float16 f16x4 __attribute__((ext_vector_type(4)));
typedef float f32x4 __attribute__((ext_vector_type(4)));
typedef int i32x4 __attribute__((ext_vector_type(4)));
typedef unsigned int u32;

// ---- ws layout (f32 element offsets; cvt_all relies on region order)
constexpr int X1C = 0;
constexpr int X2C = 409600;
constexpr int COSTC = 819200;
constexpr int WQV1C = 1139200;
constexpr int WKV2C = 1270272;
constexpr int L1C = 1401344;
constexpr int L2C = 1417728;
constexpr int ALPHAC = 1425920;
constexpr int O1WC = 1425936;
constexpr int O2WC = 1491472;
constexpr int CVT_TOTAL = 1557008;
constexpr int FLAGS = 1557008;        // 16 ints
constexpr int F32_END = 1557024;
// f16 element offsets from hb base
constexpr int QH = 0;
constexpr int KH = 409600;
constexpr int W1PACK = 819200;        // 32 tiles x 64 lanes x 8
constexpr int L2PACK = 835584;        // 16 steps x 64 lanes x 8
constexpr int MIXED = 843776;         // 5,120,000
constexpr int MIXEDT = 5963776;       // 5,120,000
constexpr int X1H = 11083776;         // 409600
constexpr int X2H = 11493376;         // 409600
constexpr int WQH = 11902976;         // 131072
constexpr int WKH = 12034048;         // 131072
constexpr int VT1 = 12165120;         // 2048 rows x 224
constexpr int VT2 = 12623872;         // 2048 rows x 224
constexpr int WV1 = 13082624;         // 409600  [b][r][256]
constexpr int WV2 = 13492224;         // 409600  [b][c][256]
constexpr int O1H = 13901824;         // 65536
constexpr int O2H = 13967360;         // 65536
constexpr size_t F16_END = 14032896;
constexpr size_t WS_NEED = (size_t)F32_END * 4 + F16_END * 2;

__device__ inline _Float16 f2h(float v) { return (_Float16)v; }
__device__ inline u32 pack2(float lo, float hi) {
  return (u32)__builtin_bit_cast(unsigned short, (_Float16)lo) |
         ((u32)__builtin_bit_cast(unsigned short, (_Float16)hi) << 16);
}
__device__ inline u32 pkrtz(float lo, float hi) {
  return __builtin_bit_cast(u32, __builtin_amdgcn_cvt_pkrtz(lo, hi));
}

__global__ void detect_kernel(const unsigned short* x1h, const unsigned char* mb,
                              int* flags) {
  int l = threadIdx.x;  // 64
  int bad = 0;
  for (int i = l; i < 256; i += 64) {
    float f = __uint_as_float(((u32)x1h[i]) << 16);
    if (!(fabsf(f) <= 1000.f)) bad = 1;  // catches NaN/inf too
  }
  unsigned long long vb = __ballot(bad);
  int nz = 0;
  for (int i = l; i < 512; i += 64)
    if ((i & 3) && mb[i]) nz = 1;
  unsigned long long vn = __ballot(nz);
  if (l == 0) {
    flags[0] = vb ? 0 : 1;  // 1 => float tensors are bf16
    flags[1] = vn ? 1 : 4;  // mask element byte size
  }
}

__global__ __launch_bounds__(256) void cvt_all_kernel(
    const void* s0, const void* s1, const void* s2, const void* s3,
    const void* s4, const void* s5, const void* s6, const void* s7,
    const void* s8, const void* s9, float* __restrict__ ws,
    _Float16* __restrict__ hb, const int* __restrict__ flags) {
  int i = blockIdx.x * 256 + threadIdx.x;
  if (i >= CVT_TOTAL) return;
  const void* src;
  int off;
  int h16 = -1;  // f16 mirror offset
  if (i < COSTC) {
    if (i < X2C) { src = s0; off = i; h16 = X1H + i; }
    else { src = s1; off = i - X2C; h16 = X2H + off; }
  } else if (i < WKV2C) {
    if (i < WQV1C) { src = s2; off = i - COSTC; }
    else { src = s3; off = i - WQV1C; h16 = WQH + off; }
  } else if (i < L2C) {
    if (i < L1C) { src = s4; off = i - WKV2C; h16 = WKH + off; }
    else { src = s5; off = i - L1C; }
  } else if (i < O1WC) {
    if (i < ALPHAC) { src = s6; off = i - L2C; }
    else { src = s7; off = i - ALPHAC; }
  } else {
    if (i < O2WC) { src = s8; off = i - O1WC; h16 = O1H + off; }
    else { src = s9; off = i - O2WC; h16 = O2H + off; }
  }
  float v = flags[0] ? __bfloat162float(((const __hip_bfloat16*)src)[off])
                     : ((const float*)src)[off];
  ws[i] = v;
  if (h16 >= 0) hb[h16] = f2h(v);
}

__global__ __launch_bounds__(256) void zpad_vt_kernel(_Float16* __restrict__ hb) {
  int i = blockIdx.x * 256 + threadIdx.x;  // 49152 = 2048 rows x 24 pad
  if (i >= 49152) return;
  int row = i / 24, c = 200 + i % 24;
  hb[VT1 + row * 224 + c] = (_Float16)0.f;
  hb[VT2 + row * 224 + c] = (_Float16)0.f;
}

// pack W1 (hidden-permuted, beta folded) + L2 fragments. grid 12x256.
__global__ __launch_bounds__(256) void pack_kernel(const float* __restrict__ L1,
                                                   const float* __restrict__ L2,
                                                   const float* __restrict__ alpha,
                                                   _Float16* __restrict__ hb) {
  int idx = blockIdx.x * 256 + threadIdx.x;
  if (idx < 2048) {  // 32 tiles x 64 lanes
    int tau = idx >> 6, l = idx & 63;
    int rho = l & 15, gg = l >> 4;
    int k2 = tau >> 1, m = tau & 1;
    int u = k2 * 32 + 8 * (rho >> 2) + 4 * m + (rho & 3);
    float beta = 0.f;
    if (gg == 2) {
#pragma unroll
      for (int h = 0; h < kH; ++h) beta += L1[u * 32 + 2 * h + 1] * alpha[h];
    }
#pragma unroll
    for (int j = 0; j < 8; ++j) {
      int feat = 8 * gg + j;
      float v = (feat < 16) ? L1[u * 32 + 2 * feat] : (feat == 16 ? beta : 0.f);
      hb[W1PACK + idx * 8 + j] = f2h(v);
    }
  } else if (idx < 3072) {  // 16 steps x 64 lanes
    int i2 = idx - 2048;
    int k2 = i2 >> 6, l = i2 & 63;
    int head = l & 15, gg = l >> 4;
#pragma unroll
    for (int j = 0; j < 8; ++j)
      hb[L2PACK + i2 * 8 + j] = f2h(L2[head * 512 + k2 * 32 + 8 * gg + j]);
  }
}

// ---- QKV as MFMA GEMM, both dirs via z: out = x(1600x256) @ W^T(256x512) ---
__global__ __launch_bounds__(256) void qkv_gemm_kernel(_Float16* __restrict__ hb) {
  const int z = blockIdx.z;
  const _Float16* x16 = hb + (z ? X2H : X1H);
  const _Float16* w16 = hb + (z ? WKH : WQH);
  _Float16* oqk = hb + (z ? KH : QH);
  _Float16* vt = hb + (z ? VT2 : VT1);
  const float scale = z ? 1.0f : 0.25f;
  const int l = threadIdx.x & 63;
  const int w = threadIdx.x >> 6;
  const int m0 = blockIdx.y * 16;
  const int c0 = blockIdx.x * 64 + w * 16;
  const int arow = m0 + (l & 15);
  const int bcol = c0 + (l & 15);
  const int kb = (l >> 4) * 8;
  const f16x8* ap = reinterpret_cast<const f16x8*>(x16 + (size_t)arow * 256 + kb);
  const f16x8* bp = reinterpret_cast<const f16x8*>(w16 + (size_t)bcol * 256 + kb);
  f32x4 acc = {0.f, 0.f, 0.f, 0.f};
#pragma unroll
  for (int s = 0; s < 8; ++s)
    acc = __builtin_amdgcn_mfma_f32_16x16x32_f16(ap[s * 4], bp[s * 4], acc, 0, 0, 0);
#pragma unroll
  for (int t = 0; t < 4; ++t) {
    int rr = m0 + (l >> 4) * 4 + t;
    int cc = c0 + (l & 15);
    int b = rr / 200, r = rr - b * 200;
    if (cc < 256) {
      oqk[((b * 16 + (cc >> 4)) * 200 + r) * 16 + (cc & 15)] = f2h(scale * acc[t]);
    } else {
      int h = (cc - 256) >> 4, d = (cc - 256) & 15;
      vt[(size_t)((b * 16 + h) * 16 + d) * 224 + r] = f2h(acc[t]);
    }
  }
}

// ---- MFMA mixed kernel: 4 waves/block, 16r x 16c tile ----------------------
// Wave wv: QK phase head-quarter hc=wv; main loop rows r = wv*4..wv*4+3,
// two interleaved chains per iteration.
__global__ __launch_bounds__(256) void mixed_mfma_kernel(
    _Float16* __restrict__ hb, const float* __restrict__ costc) {
  __shared__ _Float16 scores[4096];           // [r16][p16][f16], XOR-swizzled
  __shared__ _Float16 mixtile[16 * 16 * 20];  // [h][c][r pad 20]

  const int tid = threadIdx.x;
  const int l = tid & 63;
  const int wv = tid >> 6;
  const int p = l & 15;
  const int g = l >> 4;
  const int b = blockIdx.z;
  const int r0 = blockIdx.y * 16, c0 = blockIdx.x * 16;
  const f32x4 fzero = {0.f, 0.f, 0.f, 0.f};
  const f16x8 hzero = {0, 0, 0, 0, 0, 0, 0, 0};
  const _Float16* qh = hb + QH;
  const _Float16* kh = hb + KH;
  _Float16* mixed = hb + MIXED;
  _Float16* mixedT = hb + MIXEDT;

  // preload packed weight fragments (per wave)
  f16x8 w1f[32], l2f[16];
  {
    const f16x8* wp = reinterpret_cast<const f16x8*>(hb + W1PACK) + l;
#pragma unroll
    for (int t = 0; t < 32; ++t) w1f[t] = wp[t * 64];
    const f16x8* lp = reinterpret_cast<const f16x8*>(hb + L2PACK) + l;
#pragma unroll
    for (int t = 0; t < 16; ++t) l2f[t] = lp[t * 64];
  }

  // ---- QK phase: this wave computes its 4 heads (hc = wv)
  int qrow = r0 + p; if (qrow > 199) qrow = 199;
  int krow = c0 + p; if (krow > 199) krow = 199;
  {
    const int hc = wv;
    f32x4 acc[4];
#pragma unroll
    for (int i = 0; i < 4; ++i) {
      int h = hc * 4 + i;
      f16x8 qf = hzero, kf = hzero;
      if (g < 2) {
        qf = *reinterpret_cast<const f16x8*>(qh + ((b * 16 + h) * 200 + qrow) * 16 + 8 * g);
        kf = *reinterpret_cast<const f16x8*>(kh + ((b * 16 + h) * 200 + krow) * 16 + 8 * g);
      }
      acc[i] = __builtin_amdgcn_mfma_f32_16x16x32_f16(qf, kf, fzero, 0, 0, 0);
    }
#pragma unroll
    for (int pr = 0; pr < 2; ++pr) {
      int h = hc * 4 + pr * 2;
#pragma unroll
      for (int t = 0; t < 4; ++t) {
        u32 pk = pack2(acc[pr * 2][t], acc[pr * 2 + 1][t]);
        u32 a = (u32)((4 * g + t) * 512 + p * 32 + h * 2) ^ (((p >> 2) & 3) << 4);
        *reinterpret_cast<u32*>(reinterpret_cast<char*>(scores) + a) = pk;
      }
    }
  }
  __syncthreads();

  // ---- main loop: rows r = wv*4 + {0..3}, 2 chains per iteration
  int ccol = c0 + p; if (ccol > 199) ccol = 199;
#pragma unroll
  for (int rr = 0; rr < 4; rr += 2) {
    const int rA = wv * 4 + rr, rB = rA + 1;
    u32 aA = (u32)(rA * 512 + p * 32 + (g & 1) * 16) ^ (((p >> 2) & 3) << 4);
    u32 aB = (u32)(rB * 512 + p * 32 + (g & 1) * 16) ^ (((p >> 2) & 3) << 4);
    f16x8 sfA = *reinterpret_cast<const f16x8*>(reinterpret_cast<char*>(scores) + aA);
    f16x8 sfB = *reinterpret_cast<const f16x8*>(reinterpret_cast<char*>(scores) + aB);
    int rrA = r0 + rA; if (rrA > 199) rrA = 199;
    int rrB = r0 + rB; if (rrB > 199) rrB = 199;
    float cvA = costc[(b * 200 + rrA) * 200 + ccol];
    float cvB = costc[(b * 200 + rrB) * 200 + ccol];
    f16x8 bfA, bfB;
    if (g < 2) { bfA = sfA; bfB = sfB; }
    else if (g == 2) {
      bfA = hzero; bfA[0] = f2h(cvA);
      bfB = hzero; bfB[0] = f2h(cvB);
    } else { bfA = hzero; bfB = hzero; }

    f32x4 mA = fzero, mB = fzero;
#pragma unroll
    for (int k2 = 0; k2 < 16; ++k2) {
      f32x4 h0A = __builtin_amdgcn_mfma_f32_16x16x32_f16(w1f[2 * k2], bfA, fzero, 0, 0, 0);
      f32x4 h1A = __builtin_amdgcn_mfma_f32_16x16x32_f16(w1f[2 * k2 + 1], bfA, fzero, 0, 0, 0);
      f32x4 h0B = __builtin_amdgcn_mfma_f32_16x16x32_f16(w1f[2 * k2], bfB, fzero, 0, 0, 0);
      f32x4 h1B = __builtin_amdgcn_mfma_f32_16x16x32_f16(w1f[2 * k2 + 1], bfB, fzero, 0, 0, 0);
      i32x4 piA = {(int)pkrtz(fmaxf(h0A[0], 0.f), fmaxf(h0A[1], 0.f)),
                   (int)pkrtz(fmaxf(h0A[2], 0.f), fmaxf(h0A[3], 0.f)),
                   (int)pkrtz(fmaxf(h1A[0], 0.f), fmaxf(h1A[1], 0.f)),
                   (int)pkrtz(fmaxf(h1A[2], 0.f), fmaxf(h1A[3], 0.f))};
      i32x4 piB = {(int)pkrtz(fmaxf(h0B[0], 0.f), fmaxf(h0B[1], 0.f)),
                   (int)pkrtz(fmaxf(h0B[2], 0.f), fmaxf(h0B[3], 0.f)),
                   (int)pkrtz(fmaxf(h1B[0], 0.f), fmaxf(h1B[1], 0.f)),
                   (int)pkrtz(fmaxf(h1B[2], 0.f), fmaxf(h1B[3], 0.f))};
      mA = __builtin_amdgcn_mfma_f32_16x16x32_f16(l2f[k2], __builtin_bit_cast(f16x8, piA), mA, 0, 0, 0);
      mB = __builtin_amdgcn_mfma_f32_16x16x32_f16(l2f[k2], __builtin_bit_cast(f16x8, piB), mB, 0, 0, 0);
    }
    bool vc = (c0 + p) < 200;
    bool vrA = (r0 + rA) < 200, vrB = (r0 + rB) < 200;
#pragma unroll
    for (int t = 0; t < 4; ++t) {
      int h = 4 * g + t;
      _Float16 hA = f2h(mA[t]), hB = f2h(mB[t]);
      if (vrA && vc)
        mixed[((size_t)(b * 16 + h) * 200 + (r0 + rA)) * 200 + (c0 + p)] = hA;
      if (vrB && vc)
        mixed[((size_t)(b * 16 + h) * 200 + (r0 + rB)) * 200 + (c0 + p)] = hB;
      mixtile[(h * 16 + p) * 20 + rA] = hA;
      mixtile[(h * 16 + p) * 20 + rB] = hB;
    }
  }
  __syncthreads();

  // ---- coalesced mixedT stores: [bh][c][r]; 256 threads -> one (h,c) each
  {
    int h = tid >> 4, c = tid & 15;
    if ((c0 + c) < 200) {
      const _Float16* src = &mixtile[(h * 16 + c) * 20];
      f16x4 a0 = *reinterpret_cast<const f16x4*>(src);
      f16x4 a1 = *reinterpret_cast<const f16x4*>(src + 4);
      f16x4 a2 = *reinterpret_cast<const f16x4*>(src + 8);
      f16x4 a3 = *reinterpret_cast<const f16x4*>(src + 12);
      _Float16* dst = mixedT + ((size_t)(b * 16 + h) * 200 + (c0 + c)) * 200 + r0;
      *reinterpret_cast<f16x4*>(dst) = a0;
      *(reinterpret_cast<f16x4*>(dst) + 1) = a1;
      if (r0 + 15 < 200) {
        *(reinterpret_cast<f16x4*>(dst) + 2) = a2;
        *(reinterpret_cast<f16x4*>(dst) + 3) = a3;
      }
    }
  }
}

// ---- fused softmax + P@vT, both dirs via z ---------------------------------
// grid (13 rtile, 16 h, 16 = dir*8+b), 1 wave/block.
__global__ __launch_bounds__(64) void fused_combine_kernel(
    _Float16* __restrict__ hb, const unsigned char* __restrict__ mask,
    const int* __restrict__ flags) {
  __shared__ _Float16 wt[16 * 256];  // rows 512B, XOR-swizzled
  const int z = blockIdx.z;
  const int dir = z >> 3, b = z & 7;
  const _Float16* logits = hb + (dir ? MIXEDT : MIXED);
  const int sn = dir ? 1 : 200, sm = dir ? 200 : 1;
  const _Float16* vt = hb + (dir ? VT1 : VT2);
  _Float16* wv = hb + (dir ? WV2 : WV1);
  const int l = threadIdx.x;
  const int row = l & 15, grp = l >> 4;
  const int r0 = blockIdx.x * 16;
  const int h = blockIdx.y;
  const int bh = b * 16 + h;
  const int ms = flags[1];
  int n = r0 + row; if (n > 199) n = 199;
  const _Float16* lg = logits + ((size_t)bh * 200 + n) * 200;
  const unsigned char* mk = mask + ((size_t)b * 40000 + (size_t)n * sn) * ms;

  float xv[7][8];
  float mx = kNEG;
#pragma unroll
  for (int i = 0; i < 7; ++i) {
    int c0 = grp * 8 + i * 32;
    if (c0 < 200) {  // c0 multiple of 8 -> c0+7 <= 199
      f16x8 lv = *reinterpret_cast<const f16x8*>(lg + c0);
#pragma unroll
      for (int j = 0; j < 8; ++j) {
        bool mskd = mk[(size_t)(c0 + j) * sm * ms] != 0;
        float x = mskd ? kNEG : tanhf((float)lv[j]) * kCLIP;
        xv[i][j] = x;
        mx = fmaxf(mx, x);
      }
    } else {
#pragma unroll
      for (int j = 0; j < 8; ++j) xv[i][j] = kNEG;
    }
  }
  mx = fmaxf(mx, __shfl_xor(mx, 16));
  mx = fmaxf(mx, __shfl_xor(mx, 32));
  float se = 0.f;
#pragma unroll
  for (int i = 0; i < 7; ++i)
#pragma unroll
    for (int j = 0; j < 8; ++j) {
      float e = expf(xv[i][j] - mx);
      xv[i][j] = e;
      se += e;
    }
  se += __shfl_xor(se, 16);
  se += __shfl_xor(se, 32);
  float inv = (mx <= -1e8f) ? 0.f : 1.f / se;  // all-masked row -> zero weights
#pragma unroll
  for (int i = 0; i < 7; ++i) {
    int c0 = grp * 8 + i * 32;
    f16x8 pv;
#pragma unroll
    for (int j = 0; j < 8; ++j) pv[j] = f2h(xv[i][j] * inv);
    u32 a = (u32)(row * 512 + c0 * 2) ^ (u32)((row & 7) << 4);
    *reinterpret_cast<f16x8*>(reinterpret_cast<char*>(wt) + a) = pv;
  }
  __syncthreads();

  f32x4 acc = {0.f, 0.f, 0.f, 0.f};
#pragma unroll
  for (int k2 = 0; k2 < 7; ++k2) {
    int kb = k2 * 32 + grp * 8;
    u32 a = (u32)(row * 512 + kb * 2) ^ (u32)((row & 7) << 4);
    f16x8 af = *reinterpret_cast<const f16x8*>(reinterpret_cast<char*>(wt) + a);
    f16x8 bf = *reinterpret_cast<const f16x8*>(vt + (size_t)(bh * 16 + row) * 224 + kb);
    acc = __builtin_amdgcn_mfma_f32_16x16x32_f16(af, bf, acc, 0, 0, 0);
  }
#pragma unroll
  for (int t = 0; t < 4; ++t) {
    int r = r0 + grp * 4 + t;
    if (r < 200)
      wv[((size_t)b * 200 + r) * 256 + h * 16 + row] = f2h(acc[t]);
  }
}

// ---- out = wv(1600x256) @ Wout^T(256x256), both dirs via z ------------------
__global__ __launch_bounds__(256) void out_gemm_kernel(
    const _Float16* __restrict__ hb, void* __restrict__ out,
    const int* __restrict__ flags) {
  const int z = blockIdx.z;
  const _Float16* wvh = hb + (z ? WV2 : WV1);
  const _Float16* wout = hb + (z ? O2H : O1H);
  const int outOff = z ? 409600 : 0;
  const int l = threadIdx.x & 63;
  const int w = threadIdx.x >> 6;
  const int m0 = blockIdx.y * 16;
  const int c0 = blockIdx.x * 64 + w * 16;
  const int arow = m0 + (l & 15);
  const int bcol = c0 + (l & 15);
  const int kb = (l >> 4) * 8;
  const f16x8* ap = reinterpret_cast<const f16x8*>(wvh + (size_t)arow * 256 + kb);
  const f16x8* bp = reinterpret_cast<const f16x8*>(wout + (size_t)bcol * 256 + kb);
  f32x4 acc = {0.f, 0.f, 0.f, 0.f};
#pragma unroll
  for (int s = 0; s < 8; ++s)
    acc = __builtin_amdgcn_mfma_f32_16x16x32_f16(ap[s * 4], bp[s * 4], acc, 0, 0, 0);
  int isbf = flags[0];
#pragma unroll
  for (int t = 0; t < 4; ++t) {
    size_t oidx = (size_t)outOff + (size_t)(m0 + (l >> 4) * 4 + t) * 256 + c0 + (l & 15);
    if (isbf) ((__hip_bfloat16*)out)[oidx] = __float2bfloat16(acc[t]);
    else ((float*)out)[oidx] = acc[t];
  }
}

}  // namespace

extern "C" void kernel_launch(void* const* d_in, const int* in_sizes, int n_in,
                              void* d_out, int out_size, void* d_ws, size_t ws_size,
                              hipStream_t stream) {
  if (ws_size < WS_NEED) return;  // output stays zero -> loud failure
  const unsigned char* mask = (const unsigned char*)d_in[2];

  float* ws = (float*)d_ws;
  _Float16* hb = (_Float16*)(ws + F32_END);
  int* flags = (int*)(ws + FLAGS);

  detect_kernel<<<dim3(1), 64, 0, stream>>>((const unsigned short*)d_in[0], mask, flags);
  cvt_all_kernel<<<dim3((CVT_TOTAL + 255) / 256), 256, 0, stream>>>(
      d_in[0], d_in[1], d_in[3], d_in[4], d_in[5], d_in[6], d_in[7], d_in[8],
      d_in[9], d_in[10], ws, hb, flags);
  pack_kernel<<<dim3(12), 256, 0, stream>>>(ws + L1C, ws + L2C, ws + ALPHAC, hb);
  zpad_vt_kernel<<<dim3(192), 256, 0, stream>>>(hb);
  qkv_gemm_kernel<<<dim3(8, 100, 2), 256, 0, stream>>>(hb);
  mixed_mfma_kernel<<<dim3(13, 13, kB), 256, 0, stream>>>(hb, ws + COSTC);
  fused_combine_kernel<<<dim3(13, 16, 16), 64, 0, stream>>>(hb, mask, flags);
  out_gemm_kernel<<<dim3(4, 100, 2), 256, 0, stream>>>(hb, d_out, flags);
}

// Round 10
// 97.747 us; speedup vs baseline: 10.0920x; 1.1846x over previous
//
#include <hip/hip_runtime.h>
#include <hip/hip_bf16.h>
#include <math.h>

// EfficientMixedScoreMultiHeadAttentionLayer — round 10.
// vs round 9 (115.8us): (1) mixed repack pkrtz->pk_max_f16 (12->8 VALU per 3
// MFMA; VALUBusy 28-44% was the limiter), cost kept f16; (2) cvt_all
// vectorized x8 + detect folded in (per-wave ballot probe); (3) fused_combine
// tanh via __expf+rcp (~6 VALU vs libm ~25). Launches 8 -> 6.
// B=8, R=C=200, E=256, H=16, D=16, MS_HID=32, SDIMS=2.

namespace {
constexpr int kB = 8, kH = 16;
constexpr float kNEG = -1e9f;
constexpr float kCLIP = 10.f;

typedef _Float16 f16x8 __attribute__((ext_vector_type(8)));
typedef _Float16 f16x4 __attribute__((ext_vector_type(4)));
typedef float f32x4 __attribute__((ext_vector_type(4)));
typedef int i32x4 __attribute__((ext_vector_type(4)));
typedef unsigned short us8 __attribute__((ext_vector_type(8)));
typedef unsigned int u32;

// ---- input stream region boundaries (element index over concatenated f32/bf16 inputs)
constexpr int B1 = 409600;    // x2
constexpr int B2 = 819200;    // cost
constexpr int B3 = 1139200;   // Wqv1
constexpr int B4 = 1270272;   // Wkv2
constexpr int B5 = 1401344;   // L1
constexpr int B6 = 1417728;   // L2
constexpr int B7 = 1425920;   // alpha
constexpr int B8 = 1425936;   // o1w
constexpr int B9 = 1491472;   // o2w
constexpr int CVT_TOTAL = 1557008;

// ---- ws f32 offsets
constexpr int WL1 = 0;        // 16384
constexpr int WL2 = 16384;    // 8192
constexpr int WAL = 24576;    // 16
constexpr int FLAGS = 24592;  // 16 ints
constexpr int F32_END = 24608;
// ---- f16 element offsets from hb base
constexpr int QH = 0;
constexpr int KH = 409600;
constexpr int W1PACK = 819200;        // 32 tiles x 64 lanes x 8
constexpr int L2PACK = 835584;        // 16 steps x 64 lanes x 8
constexpr int MIXED = 843776;         // 5,120,000
constexpr int MIXEDT = 5963776;       // 5,120,000
constexpr int X1H = 11083776;         // 409600
constexpr int X2H = 11493376;         // 409600
constexpr int WQH = 11902976;         // 131072
constexpr int WKH = 12034048;         // 131072
constexpr int VT1 = 12165120;         // 2048 rows x 224
constexpr int VT2 = 12623872;         // 2048 rows x 224
constexpr int WV1 = 13082624;         // 409600  [b][r][256]
constexpr int WV2 = 13492224;         // 409600  [b][c][256]
constexpr int O1H = 13901824;         // 65536
constexpr int O2H = 13967360;         // 65536
constexpr int COSTH = 14032896;       // 320000
constexpr size_t F16_END = 14352896;
constexpr size_t WS_NEED = (size_t)F32_END * 4 + F16_END * 2;

__device__ inline _Float16 f2h(float v) { return (_Float16)v; }
__device__ inline u32 pack2(float lo, float hi) {
  return (u32)__builtin_bit_cast(unsigned short, (_Float16)lo) |
         ((u32)__builtin_bit_cast(unsigned short, (_Float16)hi) << 16);
}
__device__ inline u32 pkrtz(float lo, float hi) {
  return __builtin_bit_cast(u32, __builtin_amdgcn_cvt_pkrtz(lo, hi));
}
__device__ inline float fast_tanh(float x) {
  float t = __expf(2.f * x);
  return (t - 1.f) * __builtin_amdgcn_rcpf(t + 1.f);
}

// ---- cvt + detect: vectorized x8; flags written by block 0 wave 0 ----------
__global__ __launch_bounds__(256) void cvt_all_kernel(
    const void* s0, const void* s1, const void* s2, const void* s3,
    const void* s4, const void* s5, const void* s6, const void* s7,
    const void* s8, const void* s9, const unsigned char* __restrict__ mb,
    float* __restrict__ ws, _Float16* __restrict__ hb, int* __restrict__ flags) {
  const int lane = threadIdx.x & 63;
  // per-wave bf16 probe on x1's first 256 shorts (all lanes active)
  int bad = 0;
  const unsigned short* xp = (const unsigned short*)s0;
#pragma unroll
  for (int j = 0; j < 4; ++j) {
    float f = __uint_as_float(((u32)xp[lane * 4 + j]) << 16);
    if (!(fabsf(f) <= 1000.f)) bad = 1;  // catches NaN/inf too
  }
  const int isbf = __ballot(bad) ? 0 : 1;
  if (blockIdx.x == 0 && threadIdx.x < 64) {
    int nz = 0;
    for (int i = lane; i < 512; i += 64)
      if ((i & 3) && mb[i]) nz = 1;
    unsigned long long vn = __ballot(nz);
    if (lane == 0) { flags[0] = isbf; flags[1] = vn ? 1 : 4; }
  }
  int i = (blockIdx.x * 256 + threadIdx.x) * 8;
  if (i >= CVT_TOTAL) return;
  const void* src;
  int off, fdst = -1, hdst = -1;
  if (i < B2) {
    if (i < B1) { src = s0; off = i; hdst = X1H + off; }
    else { src = s1; off = i - B1; hdst = X2H + off; }
  } else if (i < B4) {
    if (i < B3) { src = s2; off = i - B2; hdst = COSTH + off; }
    else { src = s3; off = i - B3; hdst = WQH + off; }
  } else if (i < B6) {
    if (i < B5) { src = s4; off = i - B4; hdst = WKH + off; }
    else { src = s5; off = i - B5; fdst = WL1 + off; }
  } else if (i < B8) {
    if (i < B7) { src = s6; off = i - B6; fdst = WL2 + off; }
    else { src = s7; off = i - B7; fdst = WAL + off; }
  } else {
    if (i < B9) { src = s8; off = i - B8; hdst = O1H + off; }
    else { src = s9; off = i - B9; hdst = O2H + off; }
  }
  float v[8];
  if (isbf) {
    us8 raw = *reinterpret_cast<const us8*>((const unsigned short*)src + off);
#pragma unroll
    for (int j = 0; j < 8; ++j) v[j] = __uint_as_float(((u32)raw[j]) << 16);
  } else {
    const float4* fp = reinterpret_cast<const float4*>((const float*)src + off);
    float4 a = fp[0], b = fp[1];
    v[0] = a.x; v[1] = a.y; v[2] = a.z; v[3] = a.w;
    v[4] = b.x; v[5] = b.y; v[6] = b.z; v[7] = b.w;
  }
  if (fdst >= 0) {
    float4* d = reinterpret_cast<float4*>(ws + fdst);
    d[0] = {v[0], v[1], v[2], v[3]};
    d[1] = {v[4], v[5], v[6], v[7]};
  } else {
    f16x8 h;
#pragma unroll
    for (int j = 0; j < 8; ++j) h[j] = f2h(v[j]);
    *reinterpret_cast<f16x8*>(hb + hdst) = h;
  }
}

// ---- prep: pack W1 (hidden-permuted, beta folded) + L2 + vt zero-pad -------
__global__ __launch_bounds__(256) void prep_kernel(const float* __restrict__ L1,
                                                   const float* __restrict__ L2,
                                                   const float* __restrict__ alpha,
                                                   _Float16* __restrict__ hb) {
  int idx = blockIdx.x * 256 + threadIdx.x;
  if (idx < 2048) {  // 32 tiles x 64 lanes
    int tau = idx >> 6, l = idx & 63;
    int rho = l & 15, gg = l >> 4;
    int k2 = tau >> 1, m = tau & 1;
    int u = k2 * 32 + 8 * (rho >> 2) + 4 * m + (rho & 3);
    float beta = 0.f;
    if (gg == 2) {
#pragma unroll
      for (int h = 0; h < kH; ++h) beta += L1[u * 32 + 2 * h + 1] * alpha[h];
    }
#pragma unroll
    for (int j = 0; j < 8; ++j) {
      int feat = 8 * gg + j;
      float v = (feat < 16) ? L1[u * 32 + 2 * feat] : (feat == 16 ? beta : 0.f);
      hb[W1PACK + idx * 8 + j] = f2h(v);
    }
  } else if (idx < 3072) {  // 16 steps x 64 lanes
    int i2 = idx - 2048;
    int k2 = i2 >> 6, l = i2 & 63;
    int head = l & 15, gg = l >> 4;
#pragma unroll
    for (int j = 0; j < 8; ++j)
      hb[L2PACK + i2 * 8 + j] = f2h(L2[head * 512 + k2 * 32 + 8 * gg + j]);
  } else if (idx < 3072 + 49152) {  // vt pad: 2048 rows x 24
    int z = idx - 3072;
    int row = z / 24, c = 200 + z % 24;
    hb[VT1 + row * 224 + c] = (_Float16)0.f;
    hb[VT2 + row * 224 + c] = (_Float16)0.f;
  }
}

// ---- QKV as MFMA GEMM, both dirs via z: out = x(1600x256) @ W^T(256x512) ---
__global__ __launch_bounds__(256) void qkv_gemm_kernel(_Float16* __restrict__ hb) {
  const int z = blockIdx.z;
  const _Float16* x16 = hb + (z ? X2H : X1H);
  const _Float16* w16 = hb + (z ? WKH : WQH);
  _Float16* oqk = hb + (z ? KH : QH);
  _Float16* vt = hb + (z ? VT2 : VT1);
  const float scale = z ? 1.0f : 0.25f;
  const int l = threadIdx.x & 63;
  const int w = threadIdx.x >> 6;
  const int m0 = blockIdx.y * 16;
  const int c0 = blockIdx.x * 64 + w * 16;
  const int arow = m0 + (l & 15);
  const int bcol = c0 + (l & 15);
  const int kb = (l >> 4) * 8;
  const f16x8* ap = reinterpret_cast<const f16x8*>(x16 + (size_t)arow * 256 + kb);
  const f16x8* bp = reinterpret_cast<const f16x8*>(w16 + (size_t)bcol * 256 + kb);
  f32x4 acc = {0.f, 0.f, 0.f, 0.f};
#pragma unroll
  for (int s = 0; s < 8; ++s)
    acc = __builtin_amdgcn_mfma_f32_16x16x32_f16(ap[s * 4], bp[s * 4], acc, 0, 0, 0);
#pragma unroll
  for (int t = 0; t < 4; ++t) {
    int rr = m0 + (l >> 4) * 4 + t;
    int cc = c0 + (l & 15);
    int b = rr / 200, r = rr - b * 200;
    if (cc < 256) {
      oqk[((b * 16 + (cc >> 4)) * 200 + r) * 16 + (cc & 15)] = f2h(scale * acc[t]);
    } else {
      int h = (cc - 256) >> 4, d = (cc - 256) & 15;
      vt[(size_t)((b * 16 + h) * 16 + d) * 224 + r] = f2h(acc[t]);
    }
  }
}

// ---- MFMA mixed kernel: 4 waves/block, 16r x 16c tile ----------------------
__global__ __launch_bounds__(256) void mixed_mfma_kernel(_Float16* __restrict__ hb) {
  __shared__ _Float16 scores[4096];           // [r16][p16][f16], XOR-swizzled
  __shared__ _Float16 mixtile[16 * 16 * 20];  // [h][c][r pad 20]

  const int tid = threadIdx.x;
  const int l = tid & 63;
  const int wv = tid >> 6;
  const int p = l & 15;
  const int g = l >> 4;
  const int b = blockIdx.z;
  const int r0 = blockIdx.y * 16, c0 = blockIdx.x * 16;
  const f32x4 fzero = {0.f, 0.f, 0.f, 0.f};
  const f16x8 hzero = {0, 0, 0, 0, 0, 0, 0, 0};
  const _Float16* qh = hb + QH;
  const _Float16* kh = hb + KH;
  const _Float16* costh = hb + COSTH;
  _Float16* mixed = hb + MIXED;
  _Float16* mixedT = hb + MIXEDT;

  // preload packed weight fragments (per wave)
  f16x8 w1f[32], l2f[16];
  {
    const f16x8* wp = reinterpret_cast<const f16x8*>(hb + W1PACK) + l;
#pragma unroll
    for (int t = 0; t < 32; ++t) w1f[t] = wp[t * 64];
    const f16x8* lp = reinterpret_cast<const f16x8*>(hb + L2PACK) + l;
#pragma unroll
    for (int t = 0; t < 16; ++t) l2f[t] = lp[t * 64];
  }

  // ---- QK phase: this wave computes its 4 heads (hc = wv)
  int qrow = r0 + p; if (qrow > 199) qrow = 199;
  int krow = c0 + p; if (krow > 199) krow = 199;
  {
    const int hc = wv;
    f32x4 acc[4];
#pragma unroll
    for (int i = 0; i < 4; ++i) {
      int h = hc * 4 + i;
      f16x8 qf = hzero, kf = hzero;
      if (g < 2) {
        qf = *reinterpret_cast<const f16x8*>(qh + ((b * 16 + h) * 200 + qrow) * 16 + 8 * g);
        kf = *reinterpret_cast<const f16x8*>(kh + ((b * 16 + h) * 200 + krow) * 16 + 8 * g);
      }
      acc[i] = __builtin_amdgcn_mfma_f32_16x16x32_f16(qf, kf, fzero, 0, 0, 0);
    }
#pragma unroll
    for (int pr = 0; pr < 2; ++pr) {
      int h = hc * 4 + pr * 2;
#pragma unroll
      for (int t = 0; t < 4; ++t) {
        u32 pk = pack2(acc[pr * 2][t], acc[pr * 2 + 1][t]);
        u32 a = (u32)((4 * g + t) * 512 + p * 32 + h * 2) ^ (((p >> 2) & 3) << 4);
        *reinterpret_cast<u32*>(reinterpret_cast<char*>(scores) + a) = pk;
      }
    }
  }
  __syncthreads();

  // ---- main loop: rows r = wv*4 + {0..3}, 2 chains per iteration
  int ccol = c0 + p; if (ccol > 199) ccol = 199;
#pragma unroll
  for (int rr = 0; rr < 4; rr += 2) {
    const int rA = wv * 4 + rr, rB = rA + 1;
    u32 aA = (u32)(rA * 512 + p * 32 + (g & 1) * 16) ^ (((p >> 2) & 3) << 4);
    u32 aB = (u32)(rB * 512 + p * 32 + (g & 1) * 16) ^ (((p >> 2) & 3) << 4);
    f16x8 sfA = *reinterpret_cast<const f16x8*>(reinterpret_cast<char*>(scores) + aA);
    f16x8 sfB = *reinterpret_cast<const f16x8*>(reinterpret_cast<char*>(scores) + aB);
    int rrA = r0 + rA; if (rrA > 199) rrA = 199;
    int rrB = r0 + rB; if (rrB > 199) rrB = 199;
    _Float16 cvA = costh[(b * 200 + rrA) * 200 + ccol];
    _Float16 cvB = costh[(b * 200 + rrB) * 200 + ccol];
    f16x8 bfA, bfB;
    if (g < 2) { bfA = sfA; bfB = sfB; }
    else if (g == 2) {
      bfA = hzero; bfA[0] = cvA;
      bfB = hzero; bfB[0] = cvB;
    } else { bfA = hzero; bfB = hzero; }

    f32x4 mA = fzero, mB = fzero;
#pragma unroll
    for (int k2 = 0; k2 < 16; ++k2) {
      f32x4 h0A = __builtin_amdgcn_mfma_f32_16x16x32_f16(w1f[2 * k2], bfA, fzero, 0, 0, 0);
      f32x4 h1A = __builtin_amdgcn_mfma_f32_16x16x32_f16(w1f[2 * k2 + 1], bfA, fzero, 0, 0, 0);
      f32x4 h0B = __builtin_amdgcn_mfma_f32_16x16x32_f16(w1f[2 * k2], bfB, fzero, 0, 0, 0);
      f32x4 h1B = __builtin_amdgcn_mfma_f32_16x16x32_f16(w1f[2 * k2 + 1], bfB, fzero, 0, 0, 0);
      // convert-then-relu: RTZ is monotone, so max(cvt(x),0) == cvt(max(x,0))
      i32x4 piA = {(int)pkrtz(h0A[0], h0A[1]), (int)pkrtz(h0A[2], h0A[3]),
                   (int)pkrtz(h1A[0], h1A[1]), (int)pkrtz(h1A[2], h1A[3])};
      i32x4 piB = {(int)pkrtz(h0B[0], h0B[1]), (int)pkrtz(h0B[2], h0B[3]),
                   (int)pkrtz(h1B[0], h1B[1]), (int)pkrtz(h1B[2], h1B[3])};
      f16x8 pa = __builtin_elementwise_max(__builtin_bit_cast(f16x8, piA), hzero);
      f16x8 pb = __builtin_elementwise_max(__builtin_bit_cast(f16x8, piB), hzero);
      mA = __builtin_amdgcn_mfma_f32_16x16x32_f16(l2f[k2], pa, mA, 0, 0, 0);
      mB = __builtin_amdgcn_mfma_f32_16x16x32_f16(l2f[k2], pb, mB, 0, 0, 0);
    }
    bool vc = (c0 + p) < 200;
    bool vrA = (r0 + rA) < 200, vrB = (r0 + rB) < 200;
#pragma unroll
    for (int t = 0; t < 4; ++t) {
      int h = 4 * g + t;
      _Float16 hA = f2h(mA[t]), hB = f2h(mB[t]);
      if (vrA && vc)
        mixed[((size_t)(b * 16 + h) * 200 + (r0 + rA)) * 200 + (c0 + p)] = hA;
      if (vrB && vc)
        mixed[((size_t)(b * 16 + h) * 200 + (r0 + rB)) * 200 + (c0 + p)] = hB;
      mixtile[(h * 16 + p) * 20 + rA] = hA;
      mixtile[(h * 16 + p) * 20 + rB] = hB;
    }
  }
  __syncthreads();

  // ---- coalesced mixedT stores: [bh][c][r]; 256 threads -> one (h,c) each
  {
    int h = tid >> 4, c = tid & 15;
    if ((c0 + c) < 200) {
      const _Float16* src = &mixtile[(h * 16 + c) * 20];
      f16x4 a0 = *reinterpret_cast<const f16x4*>(src);
      f16x4 a1 = *reinterpret_cast<const f16x4*>(src + 4);
      f16x4 a2 = *reinterpret_cast<const f16x4*>(src + 8);
      f16x4 a3 = *reinterpret_cast<const f16x4*>(src + 12);
      _Float16* dst = mixedT + ((size_t)(b * 16 + h) * 200 + (c0 + c)) * 200 + r0;
      *reinterpret_cast<f16x4*>(dst) = a0;
      *(reinterpret_cast<f16x4*>(dst) + 1) = a1;
      if (r0 + 15 < 200) {
        *(reinterpret_cast<f16x4*>(dst) + 2) = a2;
        *(reinterpret_cast<f16x4*>(dst) + 3) = a3;
      }
    }
  }
}

// ---- fused softmax + P@vT, both dirs via z ---------------------------------
// grid (13 rtile, 16 h, 16 = dir*8+b), 1 wave/block.
__global__ __launch_bounds__(64) void fused_combine_kernel(
    _Float16* __restrict__ hb, const unsigned char* __restrict__ mask,
    const int* __restrict__ flags) {
  __shared__ _Float16 wt[16 * 256];  // rows 512B, XOR-swizzled
  const int z = blockIdx.z;
  const int dir = z >> 3, b = z & 7;
  const _Float16* logits = hb + (dir ? MIXEDT : MIXED);
  const int sn = dir ? 1 : 200, sm = dir ? 200 : 1;
  const _Float16* vt = hb + (dir ? VT1 : VT2);
  _Float16* wv = hb + (dir ? WV2 : WV1);
  const int l = threadIdx.x;
  const int row = l & 15, grp = l >> 4;
  const int r0 = blockIdx.x * 16;
  const int h = blockIdx.y;
  const int bh = b * 16 + h;
  const int ms = flags[1];
  int n = r0 + row; if (n > 199) n = 199;
  const _Float16* lg = logits + ((size_t)bh * 200 + n) * 200;
  const unsigned char* mk = mask + ((size_t)b * 40000 + (size_t)n * sn) * ms;

  float xv[7][8];
  float mx = kNEG;
#pragma unroll
  for (int i = 0; i < 7; ++i) {
    int c0 = grp * 8 + i * 32;
    if (c0 < 200) {  // c0 multiple of 8 -> c0+7 <= 199
      f16x8 lv = *reinterpret_cast<const f16x8*>(lg + c0);
#pragma unroll
      for (int j = 0; j < 8; ++j) {
        bool mskd = mk[(size_t)(c0 + j) * sm * ms] != 0;
        float x = mskd ? kNEG : fast_tanh((float)lv[j]) * kCLIP;
        xv[i][j] = x;
        mx = fmaxf(mx, x);
      }
    } else {
#pragma unroll
      for (int j = 0; j < 8; ++j) xv[i][j] = kNEG;
    }
  }
  mx = fmaxf(mx, __shfl_xor(mx, 16));
  mx = fmaxf(mx, __shfl_xor(mx, 32));
  float se = 0.f;
#pragma unroll
  for (int i = 0; i < 7; ++i)
#pragma unroll
    for (int j = 0; j < 8; ++j) {
      float e = __expf(xv[i][j] - mx);
      xv[i][j] = e;
      se += e;
    }
  se += __shfl_xor(se, 16);
  se += __shfl_xor(se, 32);
  float inv = (mx <= -1e8f) ? 0.f : 1.f / se;  // all-masked row -> zero weights
#pragma unroll
  for (int i = 0; i < 7; ++i) {
    int c0 = grp * 8 + i * 32;
    f16x8 pv;
#pragma unroll
    for (int j = 0; j < 8; ++j) pv[j] = f2h(xv[i][j] * inv);
    u32 a = (u32)(row * 512 + c0 * 2) ^ (u32)((row & 7) << 4);
    *reinterpret_cast<f16x8*>(reinterpret_cast<char*>(wt) + a) = pv;
  }
  __syncthreads();

  f32x4 acc = {0.f, 0.f, 0.f, 0.f};
#pragma unroll
  for (int k2 = 0; k2 < 7; ++k2) {
    int kb = k2 * 32 + grp * 8;
    u32 a = (u32)(row * 512 + kb * 2) ^ (u32)((row & 7) << 4);
    f16x8 af = *reinterpret_cast<const f16x8*>(reinterpret_cast<char*>(wt) + a);
    f16x8 bf = *reinterpret_cast<const f16x8*>(vt + (size_t)(bh * 16 + row) * 224 + kb);
    acc = __builtin_amdgcn_mfma_f32_16x16x32_f16(af, bf, acc, 0, 0, 0);
  }
#pragma unroll
  for (int t = 0; t < 4; ++t) {
    int r = r0 + grp * 4 + t;
    if (r < 200)
      wv[((size_t)b * 200 + r) * 256 + h * 16 + row] = f2h(acc[t]);
  }
}

// ---- out = wv(1600x256) @ Wout^T(256x256), both dirs via z ------------------
__global__ __launch_bounds__(256) void out_gemm_kernel(
    const _Float16* __restrict__ hb, void* __restrict__ out,
    const int* __restrict__ flags) {
  const int z = blockIdx.z;
  const _Float16* wvh = hb + (z ? WV2 : WV1);
  const _Float16* wout = hb + (z ? O2H : O1H);
  const int outOff = z ? 409600 : 0;
  const int l = threadIdx.x & 63;
  const int w = threadIdx.x >> 6;
  const int m0 = blockIdx.y * 16;
  const int c0 = blockIdx.x * 64 + w * 16;
  const int arow = m0 + (l & 15);
  const int bcol = c0 + (l & 15);
  const int kb = (l >> 4) * 8;
  const f16x8* ap = reinterpret_cast<const f16x8*>(wvh + (size_t)arow * 256 + kb);
  const f16x8* bp = reinterpret_cast<const f16x8*>(wout + (size_t)bcol * 256 + kb);
  f32x4 acc = {0.f, 0.f, 0.f, 0.f};
#pragma unroll
  for (int s = 0; s < 8; ++s)
    acc = __builtin_amdgcn_mfma_f32_16x16x32_f16(ap[s * 4], bp[s * 4], acc, 0, 0, 0);
  int isbf = flags[0];
#pragma unroll
  for (int t = 0; t < 4; ++t) {
    size_t oidx = (size_t)outOff + (size_t)(m0 + (l >> 4) * 4 + t) * 256 + c0 + (l & 15);
    if (isbf) ((__hip_bfloat16*)out)[oidx] = __float2bfloat16(acc[t]);
    else ((float*)out)[oidx] = acc[t];
  }
}

}  // namespace

extern "C" void kernel_launch(void* const* d_in, const int* in_sizes, int n_in,
                              void* d_out, int out_size, void* d_ws, size_t ws_size,
                              hipStream_t stream) {
  if (ws_size < WS_NEED) return;  // output stays zero -> loud failure
  const unsigned char* mask = (const unsigned char*)d_in[2];

  float* ws = (float*)d_ws;
  _Float16* hb = (_Float16*)(ws + F32_END);
  int* flags = (int*)(ws + FLAGS);

  cvt_all_kernel<<<dim3((CVT_TOTAL / 8 + 255) / 256), 256, 0, stream>>>(
      d_in[0], d_in[1], d_in[3], d_in[4], d_in[5], d_in[6], d_in[7], d_in[8],
      d_in[9], d_in[10], mask, ws, hb, flags);
  prep_kernel<<<dim3(204), 256, 0, stream>>>(ws + WL1, ws + WL2, ws + WAL, hb);
  qkv_gemm_kernel<<<dim3(8, 100, 2), 256, 0, stream>>>(hb);
  mixed_mfma_kernel<<<dim3(13, 13, kB), 256, 0, stream>>>(hb);
  fused_combine_kernel<<<dim3(13, 16, 16), 64, 0, stream>>>(hb, mask, flags);
  out_gemm_kernel<<<dim3(4, 100, 2), 256, 0, stream>>>(hb, d_out, flags);
}